// Round 12
// baseline (191.980 us; speedup 1.0000x reference)
//
#include <hip/hip_runtime.h>
#include <math.h>

#define B_ROWS 8192
#define DV_DIM 1024
#define DT_DIM 768
#define H_DIM 256
#define C_CLS 5
#define GH_DIM 128
#define K_NN 8
#define FD_DIM 512
#define GIP_DIM 832
#define GI_REAL 773
#define XCOLS 1797
#define NEGV -1000000000.0f
#define LN_EPS_F 1e-5f
#define BN_EPS_F 1e-5f
#define N_IMG 512
#define EW_F 0.01f
#define ALPHA_F 0.5f

typedef __attribute__((ext_vector_type(8))) short short8v;
typedef __attribute__((ext_vector_type(4))) float f32x4;

__device__ inline short bf16r(float f) {
    unsigned u = __float_as_uint(f);
    return (short)((u + 0x7fffu + ((u >> 16) & 1u)) >> 16);
}

__device__ inline float bf2f(short s) {
    return __uint_as_float(((unsigned)(unsigned short)s) << 16);
}

// ---------------- batched weight prep (single bf16) + extract fold ----------------
struct PrepArgs {
    const float* W[8];
    short* h[8];
    int K[8];
    int N[8];
    int Kpad[8];
    int cnt[8];
};

__global__ void prep_all_kernel(PrepArgs a, const float* __restrict__ x,
                                float* __restrict__ cx, float* __restrict__ cy,
                                float* __restrict__ sq, int* __restrict__ imgi,
                                int* __restrict__ cnt) {
    int idx = blockIdx.x * blockDim.x + threadIdx.x;
#pragma unroll
    for (int s = 0; s < 8; ++s) {
        if (idx < a.cnt[s]) {
            int Kp = a.Kpad[s];
            int n = idx / Kp, k = idx - n * Kp;
            float f = (k < a.K[s]) ? a.W[s][(size_t)k * a.N[s] + n] : 0.f;
            a.h[s][idx] = bf16r(f);
            return;
        }
        idx -= a.cnt[s];
    }
    if (idx < B_ROWS) {
        const float* row = x + (size_t)idx * XCOLS;
        float av = row[DV_DIM + DT_DIM];
        float bv = row[DV_DIM + DT_DIM + 1];
        cx[idx] = av; cy[idx] = bv; sq[idx] = av * av + bv * bv;
        int m = (int)row[DV_DIM + DT_DIM + 4];
        imgi[idx] = m;
        atomicAdd(&cnt[m], 1);
    }
}

// ---------------- KNN structure ----------------
__global__ void scan_kernel(const int* __restrict__ cnt, int* __restrict__ start,
                            int* __restrict__ cursor) {
    __shared__ int s[N_IMG];
    int t = threadIdx.x;
    s[t] = cnt[t];
    __syncthreads();
    for (int off = 1; off < N_IMG; off <<= 1) {
        int v = (t >= off) ? s[t - off] : 0;
        __syncthreads();
        s[t] += v;
        __syncthreads();
    }
    int st = s[t] - cnt[t];
    start[t] = st;
    cursor[t] = st;
}

__global__ void scatter_kernel(const int* __restrict__ imgi, int* __restrict__ cursor,
                               int* __restrict__ perm) {
    int i = blockIdx.x * blockDim.x + threadIdx.x;
    if (i >= B_ROWS) return;
    int pos = atomicAdd(&cursor[imgi[i]], 1);
    perm[pos] = i;
}

// ---------------- XCD swizzle helper ----------------
__device__ inline int xcd_swz(int wg, int nwg) {
    int q = nwg >> 3, r = nwg & 7;
    int xc = wg & 7, ii = wg >> 3;
    return (xc < r ? xc * (q + 1) : r * (q + 1) + (xc - r) * q) + ii;
}

// ---------------- fused LN + fv/ft GEMM (+ KNN role on blocks [0,32)) ----------------
// GEMM blocks: tile 64 rows x 64 cols, 4 waves 2x2, BK=64. A = layernorm(x seg) computed
// in-block: stats pass (sum/sumsq) then normalize+bf16 during LDS staging.
struct LnSeg {
    int xOff;            // column offset into x
    int K;               // segment width (1024 / 768)
    const float* gamma;
    const float* beta;
    const short* Bh;     // [256][K] bf16
    const float* bias;
    int colOff;          // output column offset in baseh
};

#define KNN_BLOCKS 32
#define FVFT_BLOCKS 1024  /* 512 per segment: 128 panels x 4 col-blocks */

__global__ __launch_bounds__(256) void lnfvft_kernel(
    const float* __restrict__ x, LnSeg S0, LnSeg S1, short* __restrict__ baseh,
    const float* __restrict__ cx, const float* __restrict__ cy,
    const float* __restrict__ sq, const int* __restrict__ imgi,
    const int* __restrict__ cnt, const int* __restrict__ start,
    const int* __restrict__ perm, int* __restrict__ knn_idx,
    float* __restrict__ knn_w) {
    const int tid = threadIdx.x;
    if (blockIdx.x < KNN_BLOCKS) {
        // ---- KNN role ----
        int i = blockIdx.x * 256 + tid;
        if (i >= B_ROWS) return;
        float xi = cx[i], yi = cy[i], si = sq[i];
        float vals[K_NN];
        int ids[K_NN];
#pragma unroll
        for (int k = 0; k < K_NN; ++k) { vals[k] = NEGV; ids[k] = i; }
        int m = imgi[i];
        int s = cnt[m];
        if (s >= 2) {
            int st = start[m];
            for (int t = 0; t < s; ++t) {
                int j = perm[st + t];
                if (j == i) continue;
                float d2 = si + sq[j] - 2.f * (xi * cx[j] + yi * cy[j]);
                d2 = fmaxf(d2, 0.f);
                float v = -sqrtf(d2);
                if (v > vals[K_NN - 1]) {
                    int p = K_NN - 1;
                    while (p > 0 && vals[p - 1] < v) {
                        vals[p] = vals[p - 1]; ids[p] = ids[p - 1]; --p;
                    }
                    vals[p] = v; ids[p] = j;
                }
            }
        } else {
            for (int j = 0; j < B_ROWS; ++j) {
                if (j == i) continue;
                float d2 = si + sq[j] - 2.f * (xi * cx[j] + yi * cy[j]);
                d2 = fmaxf(d2, 0.f);
                float v = -sqrtf(d2);
                if (v > vals[K_NN - 1]) {
                    int p = K_NN - 1;
                    while (p > 0 && vals[p - 1] < v) {
                        vals[p] = vals[p - 1]; ids[p] = ids[p - 1]; --p;
                    }
                    vals[p] = v; ids[p] = j;
                }
            }
        }
        float mx = vals[0];
        float e[K_NN];
        float sum = 0.f;
#pragma unroll
        for (int k = 0; k < K_NN; ++k) { e[k] = expf(vals[k] - mx); sum += e[k]; }
        float inv = 1.f / sum;
#pragma unroll
        for (int k = 0; k < K_NN; ++k) {
            knn_w[(size_t)i * K_NN + k] = e[k] * inv;
            knn_idx[(size_t)i * K_NN + k] = ids[k];
        }
        return;
    }

    // ---- fused LN+GEMM role ----
    __shared__ float smean[64];
    __shared__ float srstd[64];
    __shared__ short lds[4096 + 4096];  // A 8KB | B 8KB
    short* sAh = lds;
    short* sBh = lds + 4096;

    const int lane = tid & 63;
    const int wave = tid >> 6;
    const int wm = wave >> 1, wn = wave & 1;
    const int l15 = lane & 15, lq = lane >> 4;

    int wid = xcd_swz(blockIdx.x - KNN_BLOCKS, FVFT_BLOCKS);
    LnSeg S = S0;
    if (wid >= 512) { S = S1; wid -= 512; }
    const int panel = wid >> 2, cb = wid & 3;
    const long rowBase = (long)panel * 64;
    const int colBase = cb * 64;
    const int K = S.K;

    // ---- LN stats: 4 consecutive threads (same wave) per row ----
    {
        int r = tid >> 2, p = tid & 3;
        const float* xr = x + (rowBase + r) * (long)XCOLS + S.xOff;
        float sum = 0.f, ss = 0.f;
        int nq = K >> 2;  // float4 chunks in row
        for (int c = p; c < nq; c += 4) {
            float t4[4];
            __builtin_memcpy(t4, xr + c * 4, 16);
#pragma unroll
            for (int j = 0; j < 4; ++j) { sum += t4[j]; ss += t4[j] * t4[j]; }
        }
        sum += __shfl_xor(sum, 1);
        sum += __shfl_xor(sum, 2);
        ss += __shfl_xor(ss, 1);
        ss += __shfl_xor(ss, 2);
        if (p == 0) {
            float mean = sum / (float)K;
            float var = fmaxf(ss / (float)K - mean * mean, 0.f);
            smean[r] = mean;
            srstd[r] = rsqrtf(var + LN_EPS_F);
        }
    }
    __syncthreads();

    f32x4 acc[2][2];
#pragma unroll
    for (int i = 0; i < 2; ++i)
#pragma unroll
        for (int j = 0; j < 2; ++j) acc[i][j] = (f32x4){0.f, 0.f, 0.f, 0.f};

    const int ar0 = tid >> 3, ac = tid & 7;
    const int ar1 = ar0 + 32;

    float pAf[2][8];
    short8v pBh[2];
    // prologue prefetch (s=0)
    {
        __builtin_memcpy(pAf[0], x + (rowBase + ar0) * (long)XCOLS + S.xOff + ac * 8, 32);
        __builtin_memcpy(pAf[1], x + (rowBase + ar1) * (long)XCOLS + S.xOff + ac * 8, 32);
#pragma unroll
        for (int j = 0; j < 2; ++j) {
            int cid = tid + 256 * j;
            int cl = cid >> 3, c = cid & 7;
            pBh[j] = *(const short8v*)(S.Bh + (colBase + cl) * (long)K + c * 8);
        }
    }

    const int nsteps = K >> 6;
    for (int s = 0; s < nsteps; ++s) {
        __syncthreads();
        // stage A: normalize + pack
        {
#pragma unroll
            for (int h = 0; h < 2; ++h) {
                int ar = h ? ar1 : ar0;
                float m = smean[ar], rsd = srstd[ar];
                short8v o;
#pragma unroll
                for (int j = 0; j < 8; ++j) {
                    int col = s * 64 + ac * 8 + j;
                    o[j] = bf16r((pAf[h][j] - m) * rsd * S.gamma[col] + S.beta[col]);
                }
                *(short8v*)(sAh + ar * 64 + ((ac ^ (ar & 7)) << 3)) = o;
            }
#pragma unroll
            for (int j = 0; j < 2; ++j) {
                int cid = tid + 256 * j;
                int cl = cid >> 3, c = cid & 7;
                *(short8v*)(sBh + cl * 64 + ((c ^ (cl & 7)) << 3)) = pBh[j];
            }
        }
        __syncthreads();
        if (s + 1 < nsteps) {
            long ko = (long)(s + 1) * 64;
            __builtin_memcpy(pAf[0], x + (rowBase + ar0) * (long)XCOLS + S.xOff + ko + ac * 8, 32);
            __builtin_memcpy(pAf[1], x + (rowBase + ar1) * (long)XCOLS + S.xOff + ko + ac * 8, 32);
#pragma unroll
            for (int j = 0; j < 2; ++j) {
                int cid = tid + 256 * j;
                int cl = cid >> 3, c = cid & 7;
                pBh[j] = *(const short8v*)(S.Bh + (colBase + cl) * (long)K + ko + c * 8);
            }
        }
#pragma unroll
        for (int ksub = 0; ksub < 2; ++ksub) {
            int cc = ksub * 4 + lq;
            short8v afh[2], bfh[2];
#pragma unroll
            for (int mf = 0; mf < 2; ++mf) {
                int rr = wm * 32 + mf * 16 + l15;
                afh[mf] = *(short8v*)(sAh + rr * 64 + ((cc ^ (rr & 7)) << 3));
            }
#pragma unroll
            for (int nf = 0; nf < 2; ++nf) {
                int cl = wn * 32 + nf * 16 + l15;
                bfh[nf] = *(short8v*)(sBh + cl * 64 + ((cc ^ (cl & 7)) << 3));
            }
#pragma unroll
            for (int mf = 0; mf < 2; ++mf)
#pragma unroll
                for (int nf = 0; nf < 2; ++nf)
                    acc[mf][nf] = __builtin_amdgcn_mfma_f32_16x16x32_bf16(afh[mf], bfh[nf], acc[mf][nf], 0, 0, 0);
        }
    }

#pragma unroll
    for (int mf = 0; mf < 2; ++mf)
#pragma unroll
        for (int nf = 0; nf < 2; ++nf) {
            int col = colBase + wn * 32 + nf * 16 + l15;
            long row0 = rowBase + wm * 32 + mf * 16 + lq * 4;
#pragma unroll
            for (int rr = 0; rr < 4; ++rr) {
                long row = row0 + rr;
                float v = acc[mf][nf][rr] + S.bias[col];
                baseh[row * FD_DIM + S.colOff + col] = bf16r(v);
            }
        }
}

// ---------------- generic MFMA GEMM: tile 64 x (32*NF), 4 waves 2x2, BK=64 ----------------
// MODE 3: Ch = bf16(relu(acc+bias))
// MODE 5: Ch = bf16(bf2f(auxh)*gate + 0.5*(acc+bias))
struct GemmPair {
    const short* Ah;
    const short* Bh;
    const float* bias;
    int K; int ncb; int colOff;
};

template <int MODE, int NF>
__global__ __launch_bounds__(256) void gemm2_kernel(
    GemmPair P0, GemmPair P1, int nblk0,
    short* __restrict__ Ch, int ldc,
    const short* __restrict__ auxh, const float* __restrict__ gpv) {
    constexpr int ASZ = 4096;
    constexpr int BSZ = 32 * NF * 64;
    __shared__ short lds[ASZ + BSZ];
    short* sAh = lds;
    short* sBh = lds + ASZ;

    const int tid = threadIdx.x;
    const int lane = tid & 63;
    const int wave = tid >> 6;
    const int wm = wave >> 1, wn = wave & 1;
    const int l15 = lane & 15, lq = lane >> 4;

    int wid = xcd_swz(blockIdx.x, gridDim.x);
    GemmPair G = P0;
    if (wid >= nblk0) { G = P1; wid -= nblk0; }

    const int panel = wid / G.ncb, cb = wid - panel * G.ncb;
    const long rowBase = (long)panel * 64;
    const int colBase = cb * (32 * NF);
    const int K = G.K;

    f32x4 acc[2][NF];
#pragma unroll
    for (int i = 0; i < 2; ++i)
#pragma unroll
        for (int j = 0; j < NF; ++j) acc[i][j] = (f32x4){0.f, 0.f, 0.f, 0.f};

    short8v pAh[2], pBh[NF];
    const int ar0 = tid >> 3, ac = tid & 7;
    const int ar1 = (tid + 256) >> 3;

    {
        long go0 = (rowBase + ar0) * K + ac * 8;
        long go1 = (rowBase + ar1) * K + ac * 8;
        pAh[0] = *(const short8v*)(G.Ah + go0);
        pAh[1] = *(const short8v*)(G.Ah + go1);
#pragma unroll
        for (int j = 0; j < NF; ++j) {
            int cid = tid + 256 * j;
            int cl = cid >> 3, c = cid & 7;
            long go = (colBase + cl) * (long)K + c * 8;
            pBh[j] = *(const short8v*)(G.Bh + go);
        }
    }

    const int nsteps = K >> 6;
    for (int s = 0; s < nsteps; ++s) {
        __syncthreads();
        {
            int off0 = ar0 * 64 + ((ac ^ (ar0 & 7)) << 3);
            int off1 = ar1 * 64 + ((ac ^ (ar1 & 7)) << 3);
            *(short8v*)(sAh + off0) = pAh[0];
            *(short8v*)(sAh + off1) = pAh[1];
#pragma unroll
            for (int j = 0; j < NF; ++j) {
                int cid = tid + 256 * j;
                int cl = cid >> 3, c = cid & 7;
                int off = cl * 64 + ((c ^ (cl & 7)) << 3);
                *(short8v*)(sBh + off) = pBh[j];
            }
        }
        __syncthreads();
        if (s + 1 < nsteps) {
            long ko = (long)(s + 1) * 64;
            long go0 = (rowBase + ar0) * K + ko + ac * 8;
            long go1 = (rowBase + ar1) * K + ko + ac * 8;
            pAh[0] = *(const short8v*)(G.Ah + go0);
            pAh[1] = *(const short8v*)(G.Ah + go1);
#pragma unroll
            for (int j = 0; j < NF; ++j) {
                int cid = tid + 256 * j;
                int cl = cid >> 3, c = cid & 7;
                long go = (colBase + cl) * (long)K + ko + c * 8;
                pBh[j] = *(const short8v*)(G.Bh + go);
            }
        }
#pragma unroll
        for (int ksub = 0; ksub < 2; ++ksub) {
            int cc = ksub * 4 + lq;
            short8v afh[2], bfh[NF];
#pragma unroll
            for (int mf = 0; mf < 2; ++mf) {
                int rr = wm * 32 + mf * 16 + l15;
                int off = rr * 64 + ((cc ^ (rr & 7)) << 3);
                afh[mf] = *(short8v*)(sAh + off);
            }
#pragma unroll
            for (int nf = 0; nf < NF; ++nf) {
                int cl = wn * (NF * 16) + nf * 16 + l15;
                int off = cl * 64 + ((cc ^ (cl & 7)) << 3);
                bfh[nf] = *(short8v*)(sBh + off);
            }
#pragma unroll
            for (int mf = 0; mf < 2; ++mf)
#pragma unroll
                for (int nf = 0; nf < NF; ++nf)
                    acc[mf][nf] = __builtin_amdgcn_mfma_f32_16x16x32_bf16(afh[mf], bfh[nf], acc[mf][nf], 0, 0, 0);
        }
    }

#pragma unroll
    for (int mf = 0; mf < 2; ++mf)
#pragma unroll
        for (int nf = 0; nf < NF; ++nf) {
            int col = colBase + wn * (NF * 16) + nf * 16 + l15;
            long row0 = rowBase + wm * 32 + mf * 16 + lq * 4;
#pragma unroll
            for (int rr = 0; rr < 4; ++rr) {
                long row = row0 + rr;
                float v = acc[mf][nf][rr] + G.bias[col];
                long o = row * ldc + G.colOff + col;
                if (MODE == 3) {
                    Ch[o] = bf16r(fmaxf(v, 0.f));
                } else {  // MODE 5
                    float g = gpv[row * 2 + (col >= H_DIM ? 1 : 0)];
                    float fv = bf2f(auxh[row * FD_DIM + col]) * g + ALPHA_F * v;
                    Ch[o] = bf16r(fv);
                }
            }
        }
}

// ---------------- post_base: class prior + gi concat + neigh_agg gather ----------------
__global__ __launch_bounds__(256) void post_base_kernel(
    const short* __restrict__ baseh, const float* __restrict__ Wcp,
    const float* __restrict__ bcp, const int* __restrict__ kidx,
    const float* __restrict__ wgt, short* __restrict__ gih,
    short* __restrict__ aggh) {
    int row = blockIdx.x;
    int t = threadIdx.x;
    short sa = baseh[(size_t)row * FD_DIM + t];
    short sb = baseh[(size_t)row * FD_DIM + t + 256];
    float a = bf2f(sa), b = bf2f(sb);

    __shared__ float red[C_CLS][256];
#pragma unroll
    for (int n = 0; n < C_CLS; ++n)
        red[n][t] = a * Wcp[t * C_CLS + n] + b * Wcp[(t + 256) * C_CLS + n];
    __syncthreads();
    for (int off = 128; off; off >>= 1) {
        if (t < off) {
#pragma unroll
            for (int n = 0; n < C_CLS; ++n) red[n][t] += red[n][t + off];
        }
        __syncthreads();
    }
    size_t go = (size_t)row * GIP_DIM;
    if (t == 0) {
        float lg[C_CLS];
#pragma unroll
        for (int n = 0; n < C_CLS; ++n) lg[n] = red[n][0] + bcp[n];
        float mx = lg[0];
#pragma unroll
        for (int n = 1; n < C_CLS; ++n) mx = fmaxf(mx, lg[n]);
        float s = 0.f;
        float e[C_CLS];
#pragma unroll
        for (int n = 0; n < C_CLS; ++n) { e[n] = expf(lg[n] - mx); s += e[n]; }
        float inv = 1.f / s;
#pragma unroll
        for (int n = 0; n < C_CLS; ++n) gih[go + FD_DIM + n] = bf16r(e[n] * inv);
    }
    gih[go + t] = sa;
    gih[go + t + 256] = sb;
    if (t < GIP_DIM - GI_REAL) gih[go + GI_REAL + t] = 0;

    int jj[K_NN];
    float ww[K_NN];
#pragma unroll
    for (int k = 0; k < K_NN; ++k) {
        jj[k] = kidx[(size_t)row * K_NN + k];
        ww[k] = wgt[(size_t)row * K_NN + k];
    }
#pragma unroll
    for (int half = 0; half < 2; ++half) {
        int d = t + half * 256;
        float s = 0.f;
#pragma unroll
        for (int k = 0; k < K_NN; ++k)
            s = fmaf(ww[k], bf2f(baseh[(size_t)jj[k] * FD_DIM + d]), s);
        aggh[(size_t)row * FD_DIM + d] = bf16r(s);
    }
}

// ---------------- gated gather (spatial update input) ----------------
__global__ __launch_bounds__(256) void gather_gate_kernel(
    const short* __restrict__ baseh, const int* __restrict__ kidx,
    const float* __restrict__ wgt, const float* __restrict__ gp,
    short* __restrict__ oh) {
    int row = blockIdx.x;
    int t = threadIdx.x;
    int jj[K_NN];
    float ww[K_NN], g0[K_NN], g1[K_NN];
#pragma unroll
    for (int k = 0; k < K_NN; ++k) {
        jj[k] = kidx[(size_t)row * K_NN + k];
        ww[k] = wgt[(size_t)row * K_NN + k];
        g0[k] = gp[(size_t)jj[k] * 2 + 0];
        g1[k] = gp[(size_t)jj[k] * 2 + 1];
    }
#pragma unroll
    for (int half = 0; half < 2; ++half) {
        int d = t + half * 256;
        float s = 0.f;
#pragma unroll
        for (int k = 0; k < K_NN; ++k) {
            float f = bf2f(baseh[(size_t)jj[k] * FD_DIM + d]);
            f *= (d < H_DIM) ? g0[k] : g1[k];
            s = fmaf(ww[k], f, s);
        }
        oh[(size_t)row * FD_DIM + d] = bf16r(s);
    }
}

// ---------------- fused ctx1+ctx2: 32-row slab, N=256 full ----------------
__global__ __launch_bounds__(256) void ctxfused_kernel(
    const short* __restrict__ aggh, const short* __restrict__ wx1, const float* __restrict__ b1,
    const short* __restrict__ wx2, const float* __restrict__ b2, short* __restrict__ gih) {
    __shared__ short lds[2048 + 16384 + 8192];
    short* sA = lds;
    short* sB = lds + 2048;
    short* sH = lds + 2048 + 16384;

    const int tid = threadIdx.x;
    const int lane = tid & 63;
    const int wave = tid >> 6;
    const int l15 = lane & 15, lq = lane >> 4;
    int panel = xcd_swz(blockIdx.x, gridDim.x);
    const long rowBase = (long)panel * 32;

    const int ar = tid >> 3, ac = tid & 7;

    f32x4 acc[2][4];
#pragma unroll
    for (int i = 0; i < 2; ++i)
#pragma unroll
        for (int j = 0; j < 4; ++j) acc[i][j] = (f32x4){0.f, 0.f, 0.f, 0.f};

    short8v pA, pB[8];
    {
        pA = *(const short8v*)(aggh + (rowBase + ar) * 512 + ac * 8);
#pragma unroll
        for (int j = 0; j < 8; ++j) {
            int cid = tid + 256 * j;
            int cl = cid >> 3, c = cid & 7;
            pB[j] = *(const short8v*)(wx1 + (long)cl * 512 + c * 8);
        }
    }
    for (int s = 0; s < 8; ++s) {
        __syncthreads();
        *(short8v*)(sA + ar * 64 + ((ac ^ (ar & 7)) << 3)) = pA;
#pragma unroll
        for (int j = 0; j < 8; ++j) {
            int cid = tid + 256 * j;
            int cl = cid >> 3, c = cid & 7;
            *(short8v*)(sB + cl * 64 + ((c ^ (cl & 7)) << 3)) = pB[j];
        }
        __syncthreads();
        if (s + 1 < 8) {
            long ko = (long)(s + 1) * 64;
            pA = *(const short8v*)(aggh + (rowBase + ar) * 512 + ko + ac * 8);
#pragma unroll
            for (int j = 0; j < 8; ++j) {
                int cid = tid + 256 * j;
                int cl = cid >> 3, c = cid & 7;
                pB[j] = *(const short8v*)(wx1 + (long)cl * 512 + ko + c * 8);
            }
        }
#pragma unroll
        for (int ksub = 0; ksub < 2; ++ksub) {
            int cc = ksub * 4 + lq;
            short8v af[2], bf[4];
#pragma unroll
            for (int mf = 0; mf < 2; ++mf) {
                int rr = mf * 16 + l15;
                af[mf] = *(short8v*)(sA + rr * 64 + ((cc ^ (rr & 7)) << 3));
            }
#pragma unroll
            for (int nf = 0; nf < 4; ++nf) {
                int cl = wave * 64 + nf * 16 + l15;
                bf[nf] = *(short8v*)(sB + cl * 64 + ((cc ^ (cl & 7)) << 3));
            }
#pragma unroll
            for (int mf = 0; mf < 2; ++mf)
#pragma unroll
                for (int nf = 0; nf < 4; ++nf)
                    acc[mf][nf] = __builtin_amdgcn_mfma_f32_16x16x32_bf16(af[mf], bf[nf], acc[mf][nf], 0, 0, 0);
        }
    }
    __syncthreads();
#pragma unroll
    for (int mf = 0; mf < 2; ++mf)
#pragma unroll
        for (int nf = 0; nf < 4; ++nf) {
            int col = wave * 64 + nf * 16 + l15;
            int sub = col >> 6, cch = (col >> 3) & 7, ce = col & 7;
#pragma unroll
            for (int rr = 0; rr < 4; ++rr) {
                int r = mf * 16 + lq * 4 + rr;
                float v = fmaxf(acc[mf][nf][rr] + b1[col], 0.f);
                sH[sub * 2048 + r * 64 + ((cch ^ (r & 7)) << 3) + ce] = bf16r(v);
            }
        }
    f32x4 acc2[2][4];
#pragma unroll
    for (int i = 0; i < 2; ++i)
#pragma unroll
        for (int j = 0; j < 4; ++j) acc2[i][j] = (f32x4){0.f, 0.f, 0.f, 0.f};
    for (int s = 0; s < 4; ++s) {
        __syncthreads();
#pragma unroll
        for (int j = 0; j < 8; ++j) {
            int cid = tid + 256 * j;
            int cl = cid >> 3, c = cid & 7;
            short8v b = *(const short8v*)(wx2 + (long)cl * 256 + s * 64 + c * 8);
            *(short8v*)(sB + cl * 64 + ((c ^ (cl & 7)) << 3)) = b;
        }
        __syncthreads();
#pragma unroll
        for (int ksub = 0; ksub < 2; ++ksub) {
            int cc = ksub * 4 + lq;
            short8v af[2], bf[4];
#pragma unroll
            for (int mf = 0; mf < 2; ++mf) {
                int rr = mf * 16 + l15;
                af[mf] = *(short8v*)(sH + s * 2048 + rr * 64 + ((cc ^ (rr & 7)) << 3));
            }
#pragma unroll
            for (int nf = 0; nf < 4; ++nf) {
                int cl = wave * 64 + nf * 16 + l15;
                bf[nf] = *(short8v*)(sB + cl * 64 + ((cc ^ (cl & 7)) << 3));
            }
#pragma unroll
            for (int mf = 0; mf < 2; ++mf)
#pragma unroll
                for (int nf = 0; nf < 4; ++nf)
                    acc2[mf][nf] = __builtin_amdgcn_mfma_f32_16x16x32_bf16(af[mf], bf[nf], acc2[mf][nf], 0, 0, 0);
        }
    }
#pragma unroll
    for (int mf = 0; mf < 2; ++mf)
#pragma unroll
        for (int nf = 0; nf < 4; ++nf) {
            int col = wave * 64 + nf * 16 + l15;
#pragma unroll
            for (int rr = 0; rr < 4; ++rr) {
                long row = rowBase + mf * 16 + lq * 4 + rr;
                gih[row * GIP_DIM + FD_DIM + C_CLS + col] = bf16r(acc2[mf][nf][rr] + b2[col]);
            }
        }
}

// ---------------- fused g1 + gate head: 64x128 block, K=832 ----------------
__global__ __launch_bounds__(256) void g1gate_kernel(
    const short* __restrict__ gih, const short* __restrict__ wg1, const float* __restrict__ b1,
    const float* __restrict__ W2, const float* __restrict__ b2,
    float* __restrict__ gp, float* __restrict__ entpart) {
    __shared__ float hls[64 * 128];
    short* sA = (short*)hls;
    short* sB = sA + 4096;
    __shared__ float entrow[64];

    const int tid = threadIdx.x;
    const int lane = tid & 63;
    const int wave = tid >> 6;
    const int wm = wave >> 1, wn = wave & 1;
    const int l15 = lane & 15, lq = lane >> 4;
    int panel = xcd_swz(blockIdx.x, gridDim.x);
    const long rowBase = (long)panel * 64;

    const int ar0 = tid >> 3, ac = tid & 7;
    const int ar1 = (tid + 256) >> 3;
    constexpr int K = GIP_DIM;

    f32x4 acc[2][4];
#pragma unroll
    for (int i = 0; i < 2; ++i)
#pragma unroll
        for (int j = 0; j < 4; ++j) acc[i][j] = (f32x4){0.f, 0.f, 0.f, 0.f};

    short8v pA0, pA1, pB[4];
    {
        pA0 = *(const short8v*)(gih + (rowBase + ar0) * K + ac * 8);
        pA1 = *(const short8v*)(gih + (rowBase + ar1) * K + ac * 8);
#pragma unroll
        for (int j = 0; j < 4; ++j) {
            int cid = tid + 256 * j;
            int cl = cid >> 3, c = cid & 7;
            pB[j] = *(const short8v*)(wg1 + (long)cl * K + c * 8);
        }
    }
    const int nsteps = K >> 6;  // 13
    for (int s = 0; s < nsteps; ++s) {
        __syncthreads();
        *(short8v*)(sA + ar0 * 64 + ((ac ^ (ar0 & 7)) << 3)) = pA0;
        *(short8v*)(sA + ar1 * 64 + ((ac ^ (ar1 & 7)) << 3)) = pA1;
#pragma unroll
        for (int j = 0; j < 4; ++j) {
            int cid = tid + 256 * j;
            int cl = cid >> 3, c = cid & 7;
            *(short8v*)(sB + cl * 64 + ((c ^ (cl & 7)) << 3)) = pB[j];
        }
        __syncthreads();
        if (s + 1 < nsteps) {
            long ko = (long)(s + 1) * 64;
            pA0 = *(const short8v*)(gih + (rowBase + ar0) * K + ko + ac * 8);
            pA1 = *(const short8v*)(gih + (rowBase + ar1) * K + ko + ac * 8);
#pragma unroll
            for (int j = 0; j < 4; ++j) {
                int cid = tid + 256 * j;
                int cl = cid >> 3, c = cid & 7;
                pB[j] = *(const short8v*)(wg1 + (long)cl * K + ko + c * 8);
            }
        }
#pragma unroll
        for (int ksub = 0; ksub < 2; ++ksub) {
            int cc = ksub * 4 + lq;
            short8v af[2], bf[4];
#pragma unroll
            for (int mf = 0; mf < 2; ++mf) {
                int rr = wm * 32 + mf * 16 + l15;
                af[mf] = *(short8v*)(sA + rr * 64 + ((cc ^ (rr & 7)) << 3));
            }
#pragma unroll
            for (int nf = 0; nf < 4; ++nf) {
                int cl = wn * 64 + nf * 16 + l15;
                bf[nf] = *(short8v*)(sB + cl * 64 + ((cc ^ (cl & 7)) << 3));
            }
#pragma unroll
            for (int mf = 0; mf < 2; ++mf)
#pragma unroll
                for (int nf = 0; nf < 4; ++nf)
                    acc[mf][nf] = __builtin_amdgcn_mfma_f32_16x16x32_bf16(af[mf], bf[nf], acc[mf][nf], 0, 0, 0);
        }
    }
    __syncthreads();
#pragma unroll
    for (int mf = 0; mf < 2; ++mf)
#pragma unroll
        for (int nf = 0; nf < 4; ++nf) {
            int col = wn * 64 + nf * 16 + l15;
#pragma unroll
            for (int rr = 0; rr < 4; ++rr) {
                int r = wm * 32 + mf * 16 + lq * 4 + rr;
                hls[r * 128 + col] = fmaxf(acc[mf][nf][rr] + b1[col], 0.f);
            }
        }
    __syncthreads();
    {
        int r = tid >> 2, p = tid & 3;
        float a0 = 0.f, a1 = 0.f;
#pragma unroll
        for (int i = 0; i < 32; ++i) {
            int c = p + i * 4;
            float hv = hls[r * 128 + c];
            a0 = fmaf(hv, W2[c * 2 + 0], a0);
            a1 = fmaf(hv, W2[c * 2 + 1], a1);
        }
        a0 += __shfl_xor(a0, 1); a1 += __shfl_xor(a1, 1);
        a0 += __shfl_xor(a0, 2); a1 += __shfl_xor(a1, 2);
        if (p == 0) {
            float l0 = a0 + b2[0], l1 = a1 + b2[1];
            float mx = fmaxf(l0, l1);
            float e0 = expf(l0 - mx), e1 = expf(l1 - mx);
            float ssum = e0 + e1;
            float p0 = e0 / ssum, p1 = e1 / ssum;
            long grow = rowBase + r;
            gp[grow * 2 + 0] = p0;
            gp[grow * 2 + 1] = p1;
            entrow[r] = -(p0 * logf(p0 + 1e-8f) + p1 * logf(p1 + 1e-8f));
        }
    }
    __syncthreads();
    if (tid == 0) {
        float s = 0.f;
        for (int r = 0; r < 64; ++r) s += entrow[r];
        entpart[blockIdx.x] = s;
    }
}

// ---------------- fused c1 + BN + relu + logits (+ entropy finalize) ----------------
__global__ __launch_bounds__(256) void c1logits_kernel(
    const short* __restrict__ fusedh, const short* __restrict__ wc1, const float* __restrict__ b1,
    const float* __restrict__ bng, const float* __restrict__ bnb,
    const float* __restrict__ W2, const float* __restrict__ b2,
    const float* __restrict__ entpart, float* __restrict__ out) {
    __shared__ short lds[2048 + 16384];
    short* sA = lds;
    short* sB = lds + 2048;
    float* hls = (float*)lds;

    const int tid = threadIdx.x;
    const int lane = tid & 63;
    const int wave = tid >> 6;
    const int l15 = lane & 15, lq = lane >> 4;
    int panel = xcd_swz(blockIdx.x, gridDim.x);
    const long rowBase = (long)panel * 32;
    const int ar = tid >> 3, ac = tid & 7;

    f32x4 acc[2][4];
#pragma unroll
    for (int i = 0; i < 2; ++i)
#pragma unroll
        for (int j = 0; j < 4; ++j) acc[i][j] = (f32x4){0.f, 0.f, 0.f, 0.f};

    short8v pA, pB[8];
    {
        pA = *(const short8v*)(fusedh + (rowBase + ar) * 512 + ac * 8);
#pragma unroll
        for (int j = 0; j < 8; ++j) {
            int cid = tid + 256 * j;
            int cl = cid >> 3, c = cid & 7;
            pB[j] = *(const short8v*)(wc1 + (long)cl * 512 + c * 8);
        }
    }
    for (int s = 0; s < 8; ++s) {
        __syncthreads();
        *(short8v*)(sA + ar * 64 + ((ac ^ (ar & 7)) << 3)) = pA;
#pragma unroll
        for (int j = 0; j < 8; ++j) {
            int cid = tid + 256 * j;
            int cl = cid >> 3, c = cid & 7;
            *(short8v*)(sB + cl * 64 + ((c ^ (cl & 7)) << 3)) = pB[j];
        }
        __syncthreads();
        if (s + 1 < 8) {
            long ko = (long)(s + 1) * 64;
            pA = *(const short8v*)(fusedh + (rowBase + ar) * 512 + ko + ac * 8);
#pragma unroll
            for (int j = 0; j < 8; ++j) {
                int cid = tid + 256 * j;
                int cl = cid >> 3, c = cid & 7;
                pB[j] = *(const short8v*)(wc1 + (long)cl * 512 + ko + c * 8);
            }
        }
#pragma unroll
        for (int ksub = 0; ksub < 2; ++ksub) {
            int cc = ksub * 4 + lq;
            short8v af[2], bf[4];
#pragma unroll
            for (int mf = 0; mf < 2; ++mf) {
                int rr = mf * 16 + l15;
                af[mf] = *(short8v*)(sA + rr * 64 + ((cc ^ (rr & 7)) << 3));
            }
#pragma unroll
            for (int nf = 0; nf < 4; ++nf) {
                int cl = wave * 64 + nf * 16 + l15;
                bf[nf] = *(short8v*)(sB + cl * 64 + ((cc ^ (cl & 7)) << 3));
            }
#pragma unroll
            for (int mf = 0; mf < 2; ++mf)
#pragma unroll
                for (int nf = 0; nf < 4; ++nf)
                    acc[mf][nf] = __builtin_amdgcn_mfma_f32_16x16x32_bf16(af[mf], bf[nf], acc[mf][nf], 0, 0, 0);
        }
    }
    __syncthreads();
#pragma unroll
    for (int mf = 0; mf < 2; ++mf)
#pragma unroll
        for (int nf = 0; nf < 4; ++nf) {
            int col = wave * 64 + nf * 16 + l15;
            float scale = bng[col] * rsqrtf(1.f + BN_EPS_F);
            float shift = bnb[col];
#pragma unroll
            for (int rr = 0; rr < 4; ++rr) {
                int r = mf * 16 + lq * 4 + rr;
                float v = (acc[mf][nf][rr] + b1[col]) * scale + shift;
                hls[r * 256 + col] = fmaxf(v, 0.f);
            }
        }
    __syncthreads();
    {
        int r = tid >> 3, p = tid & 7;
        float a[C_CLS];
#pragma unroll
        for (int n = 0; n < C_CLS; ++n) a[n] = 0.f;
#pragma unroll
        for (int i = 0; i < 32; ++i) {
            int c = p + i * 8;
            float hv = hls[r * 256 + c];
#pragma unroll
            for (int n = 0; n < C_CLS; ++n) a[n] = fmaf(hv, W2[c * 5 + n], a[n]);
        }
#pragma unroll
        for (int n = 0; n < C_CLS; ++n) {
            a[n] += __shfl_xor(a[n], 1);
            a[n] += __shfl_xor(a[n], 2);
            a[n] += __shfl_xor(a[n], 4);
        }
        if (p == 0) {
            long grow = rowBase + r;
#pragma unroll
            for (int n = 0; n < C_CLS; ++n) out[grow * C_CLS + n] = a[n] + b2[n];
        }
    }
    if (blockIdx.x == 0 && tid < 64) {
        float s = entpart[tid] + entpart[tid + 64];
        for (int off = 32; off; off >>= 1) s += __shfl_down(s, off);
        if (tid == 0) out[(size_t)B_ROWS * C_CLS] = s * (EW_F / (float)B_ROWS);
    }
}

extern "C" void kernel_launch(void* const* d_in, const int* in_sizes, int n_in,
                              void* d_out, int out_size, void* d_ws, size_t ws_size,
                              hipStream_t stream) {
    const float* x = (const float*)d_in[0];
    const float* ln_v_g = (const float*)d_in[1];
    const float* ln_v_b = (const float*)d_in[2];
    const float* ln_t_g = (const float*)d_in[3];
    const float* ln_t_b = (const float*)d_in[4];
    const float* W_v = (const float*)d_in[5];
    const float* b_v = (const float*)d_in[6];
    const float* W_t = (const float*)d_in[7];
    const float* b_t = (const float*)d_in[8];
    const float* W_cp = (const float*)d_in[9];
    const float* b_cp = (const float*)d_in[10];
    const float* W_ctx1 = (const float*)d_in[11];
    const float* b_ctx1 = (const float*)d_in[12];
    const float* W_ctx2 = (const float*)d_in[13];
    const float* b_ctx2 = (const float*)d_in[14];
    const float* W_g1 = (const float*)d_in[15];
    const float* b_g1 = (const float*)d_in[16];
    const float* W_g2 = (const float*)d_in[17];
    const float* b_g2 = (const float*)d_in[18];
    const float* W_gu1 = (const float*)d_in[19];
    const float* b_gu1 = (const float*)d_in[20];
    const float* W_gu2 = (const float*)d_in[21];
    const float* b_gu2 = (const float*)d_in[22];
    const float* W_c1 = (const float*)d_in[23];
    const float* b_c1 = (const float*)d_in[24];
    const float* bn_g = (const float*)d_in[25];
    const float* bn_b = (const float*)d_in[26];
    const float* W_c2 = (const float*)d_in[27];
    const float* b_c2 = (const float*)d_in[28];

    float* out = (float*)d_out;

    // ---- workspace arena ----
    char* wsb = (char*)d_ws;
    size_t off = 0;
    auto alloc = [&](size_t bytes) {
        char* p = wsb + off;
        off += (bytes + 255) & ~(size_t)255;
        return p;
    };
    short* baseh = (short*)alloc((size_t)B_ROWS * FD_DIM * 2);
    short* aggh = (short*)alloc((size_t)B_ROWS * FD_DIM * 2);  // agg / fusedh
    short* guh = (short*)alloc((size_t)B_ROWS * FD_DIM * 2);
    short* gih = (short*)alloc((size_t)B_ROWS * GIP_DIM * 2);
    float* gp = (float*)alloc((size_t)B_ROWS * 2 * 4);
    float* entpart = (float*)alloc(128 * 4);
    float* cxv = (float*)alloc((size_t)B_ROWS * 4);
    float* cyv = (float*)alloc((size_t)B_ROWS * 4);
    float* sqv = (float*)alloc((size_t)B_ROWS * 4);
    float* wgt = (float*)alloc((size_t)B_ROWS * K_NN * 4);
    int* imgi = (int*)alloc((size_t)B_ROWS * 4);
    int* cnt = (int*)alloc(N_IMG * 4);
    int* startb = (int*)alloc(N_IMG * 4);
    int* cursor = (int*)alloc(N_IMG * 4);
    int* perm = (int*)alloc((size_t)B_ROWS * 4);
    int* kidx = (int*)alloc((size_t)B_ROWS * K_NN * 4);
    short* wv_h = (short*)alloc(256 * 1024 * 2);
    short* wt_h = (short*)alloc(256 * 768 * 2);
    short* wx1_h = (short*)alloc(256 * 512 * 2);
    short* wx2_h = (short*)alloc(256 * 256 * 2);
    short* wg1_h = (short*)alloc(128 * GIP_DIM * 2);
    short* wu1_h = (short*)alloc(512 * 512 * 2);
    short* wu2_h = (short*)alloc(512 * 512 * 2);
    short* wc1_h = (short*)alloc(256 * 512 * 2);
    short* fusedh = aggh;

    dim3 blk(256);
    dim3 gridRows((B_ROWS + 255) / 256);

    // ---- weight prep + extract (one launch) ----
    PrepArgs pa;
    const float* pw[8] = {W_v, W_t, W_ctx1, W_ctx2, W_g1, W_gu1, W_gu2, W_c1};
    short* ph[8] = {wv_h, wt_h, wx1_h, wx2_h, wg1_h, wu1_h, wu2_h, wc1_h};
    int pK[8] = {1024, 768, 512, 256, GI_REAL, 512, 512, 512};
    int pN[8] = {256, 256, 256, 256, 128, 512, 512, 256};
    int pKp[8] = {1024, 768, 512, 256, GIP_DIM, 512, 512, 512};
    int total = 0;
    for (int s = 0; s < 8; ++s) {
        pa.W[s] = pw[s]; pa.h[s] = ph[s];
        pa.K[s] = pK[s]; pa.N[s] = pN[s]; pa.Kpad[s] = pKp[s];
        pa.cnt[s] = pN[s] * pKp[s];
        total += pa.cnt[s];
    }
    hipMemsetAsync(cnt, 0, N_IMG * sizeof(int), stream);
    prep_all_kernel<<<(total + B_ROWS + 255) / 256, blk, 0, stream>>>(
        pa, x, cxv, cyv, sqv, imgi, cnt);

    // ---- KNN buckets ----
    scan_kernel<<<1, N_IMG, 0, stream>>>(cnt, startb, cursor);
    scatter_kernel<<<gridRows, blk, 0, stream>>>(imgi, cursor, perm);

    // ---- fused LN + fv/ft GEMM (+ KNN top-8 on blocks 0..31) ----
    LnSeg S0{0, DV_DIM, ln_v_g, ln_v_b, wv_h, b_v, 0};
    LnSeg S1{DV_DIM, DT_DIM, ln_t_g, ln_t_b, wt_h, b_t, 256};
    lnfvft_kernel<<<KNN_BLOCKS + FVFT_BLOCKS, blk, 0, stream>>>(
        x, S0, S1, baseh, cxv, cyv, sqv, imgi, cnt, startb, perm, kidx, wgt);

    // ---- class prior + gi concat + neigh_agg ----
    post_base_kernel<<<B_ROWS, blk, 0, stream>>>(baseh, W_cp, b_cp, kidx, wgt, gih, aggh);

    // ---- ctx1+ctx2 fused -> gi[:, 517:773] ----
    ctxfused_kernel<<<256, blk, 0, stream>>>(aggh, wx1_h, b_ctx1, wx2_h, b_ctx2, gih);

    // ---- g1 + gate fused ----
    g1gate_kernel<<<128, blk, 0, stream>>>(gih, wg1_h, b_g1, W_g2, b_g2, gp, entpart);

    // ---- spatial update (separate u1/u2 GEMMs, 64-row panels for weight reuse) ----
    gather_gate_kernel<<<B_ROWS, blk, 0, stream>>>(baseh, kidx, wgt, gp, aggh);
    GemmPair u1P{aggh, wu1_h, b_gu1, 512, 4, 0};
    gemm2_kernel<3, 4><<<512, blk, 0, stream>>>(u1P, u1P, 512, guh, FD_DIM,
                                                nullptr, nullptr);
    GemmPair u2P{guh, wu2_h, b_gu2, 512, 4, 0};
    gemm2_kernel<5, 4><<<512, blk, 0, stream>>>(u2P, u2P, 512, fusedh, FD_DIM,
                                                baseh, gp);

    // ---- classifier head fused (+ entropy finalize) ----
    c1logits_kernel<<<256, blk, 0, stream>>>(fusedh, wc1_h, b_c1, bn_g, bn_b,
                                             W_c2, b_c2, entpart, out);

    (void)in_sizes; (void)n_in; (void)out_size; (void)ws_size;
}

// Round 13
// 170.141 us; speedup vs baseline: 1.1284x; 1.1284x over previous
//
#include <hip/hip_runtime.h>
#include <math.h>

#define B_ROWS 8192
#define DV_DIM 1024
#define DT_DIM 768
#define H_DIM 256
#define C_CLS 5
#define GH_DIM 128
#define K_NN 8
#define FD_DIM 512
#define GIP_DIM 832
#define GI_REAL 773
#define XCOLS 1797
#define NEGV -1000000000.0f
#define LN_EPS_F 1e-5f
#define BN_EPS_F 1e-5f
#define N_IMG 512
#define EW_F 0.01f
#define ALPHA_F 0.5f

typedef __attribute__((ext_vector_type(8))) short short8v;
typedef __attribute__((ext_vector_type(4))) float f32x4;

__device__ inline short bf16r(float f) {
    unsigned u = __float_as_uint(f);
    return (short)((u + 0x7fffu + ((u >> 16) & 1u)) >> 16);
}

__device__ inline float bf2f(short s) {
    return __uint_as_float(((unsigned)(unsigned short)s) << 16);
}

// ---------------- coordinate extract (feeds scan/scatter) ----------------
__global__ void extract_kernel(const float* __restrict__ x,
                               float* __restrict__ cx, float* __restrict__ cy,
                               float* __restrict__ sq, int* __restrict__ imgi,
                               int* __restrict__ cnt) {
    int i = blockIdx.x * blockDim.x + threadIdx.x;
    if (i >= B_ROWS) return;
    const float* row = x + (size_t)i * XCOLS;
    float a = row[DV_DIM + DT_DIM];
    float b = row[DV_DIM + DT_DIM + 1];
    cx[i] = a; cy[i] = b; sq[i] = a * a + b * b;
    int m = (int)row[DV_DIM + DT_DIM + 4];
    imgi[i] = m;
    atomicAdd(&cnt[m], 1);
}

// ---------------- KNN structure ----------------
__global__ void scan_kernel(const int* __restrict__ cnt, int* __restrict__ start,
                            int* __restrict__ cursor) {
    __shared__ int s[N_IMG];
    int t = threadIdx.x;
    s[t] = cnt[t];
    __syncthreads();
    for (int off = 1; off < N_IMG; off <<= 1) {
        int v = (t >= off) ? s[t - off] : 0;
        __syncthreads();
        s[t] += v;
        __syncthreads();
    }
    int st = s[t] - cnt[t];
    start[t] = st;
    cursor[t] = st;
}

__global__ void scatter_kernel(const int* __restrict__ imgi, int* __restrict__ cursor,
                               int* __restrict__ perm) {
    int i = blockIdx.x * blockDim.x + threadIdx.x;
    if (i >= B_ROWS) return;
    int pos = atomicAdd(&cursor[imgi[i]], 1);
    perm[pos] = i;
}

// ---------------- multi-role mega dispatch:
// blocks [0,32)                : KNN top-8 (latency-bound)
// blocks [32, 32+2048)         : LN wave-per-row (BW/latency-bound)
// blocks [32+2048, ...)        : weight prep bf16 transpose (latency-bound)
// All three roles are mutually independent -> they co-schedule on the CUs.
#define KNN_BLOCKS 32
#define LN_BLOCKS (B_ROWS / 4)
struct PrepArgs {
    const float* W[8];
    short* h[8];
    int K[8];
    int N[8];
    int Kpad[8];
    int cnt[8];
};

__global__ __launch_bounds__(256) void lnknnprep_kernel(
    const float* __restrict__ x,
    const float* __restrict__ gv, const float* __restrict__ bv,
    const float* __restrict__ gt, const float* __restrict__ bt,
    short* __restrict__ xvh, short* __restrict__ xth,
    const float* __restrict__ cx, const float* __restrict__ cy,
    const float* __restrict__ sq, const int* __restrict__ imgi,
    const int* __restrict__ cnt, const int* __restrict__ start,
    const int* __restrict__ perm, int* __restrict__ knn_idx,
    float* __restrict__ knn_w, PrepArgs pa) {
    if (blockIdx.x >= KNN_BLOCKS + LN_BLOCKS) {
        // ---- weight prep role ----
        int idx = (blockIdx.x - KNN_BLOCKS - LN_BLOCKS) * 256 + threadIdx.x;
#pragma unroll
        for (int s = 0; s < 8; ++s) {
            if (idx < pa.cnt[s]) {
                int Kp = pa.Kpad[s];
                int n = idx / Kp, k = idx - n * Kp;
                float f = (k < pa.K[s]) ? pa.W[s][(size_t)k * pa.N[s] + n] : 0.f;
                pa.h[s][idx] = bf16r(f);
                return;
            }
            idx -= pa.cnt[s];
        }
        return;
    }
    if (blockIdx.x < KNN_BLOCKS) {
        // ---- KNN role ----
        int i = blockIdx.x * 256 + threadIdx.x;
        if (i >= B_ROWS) return;
        float xi = cx[i], yi = cy[i], si = sq[i];
        float vals[K_NN];
        int ids[K_NN];
#pragma unroll
        for (int k = 0; k < K_NN; ++k) { vals[k] = NEGV; ids[k] = i; }
        int m = imgi[i];
        int s = cnt[m];
        if (s >= 2) {
            int st = start[m];
            for (int t = 0; t < s; ++t) {
                int j = perm[st + t];
                if (j == i) continue;
                float d2 = si + sq[j] - 2.f * (xi * cx[j] + yi * cy[j]);
                d2 = fmaxf(d2, 0.f);
                float v = -sqrtf(d2);
                if (v > vals[K_NN - 1]) {
                    int p = K_NN - 1;
                    while (p > 0 && vals[p - 1] < v) {
                        vals[p] = vals[p - 1]; ids[p] = ids[p - 1]; --p;
                    }
                    vals[p] = v; ids[p] = j;
                }
            }
        } else {
            for (int j = 0; j < B_ROWS; ++j) {
                if (j == i) continue;
                float d2 = si + sq[j] - 2.f * (xi * cx[j] + yi * cy[j]);
                d2 = fmaxf(d2, 0.f);
                float v = -sqrtf(d2);
                if (v > vals[K_NN - 1]) {
                    int p = K_NN - 1;
                    while (p > 0 && vals[p - 1] < v) {
                        vals[p] = vals[p - 1]; ids[p] = ids[p - 1]; --p;
                    }
                    vals[p] = v; ids[p] = j;
                }
            }
        }
        float mx = vals[0];
        float e[K_NN];
        float sum = 0.f;
#pragma unroll
        for (int k = 0; k < K_NN; ++k) { e[k] = expf(vals[k] - mx); sum += e[k]; }
        float inv = 1.f / sum;
#pragma unroll
        for (int k = 0; k < K_NN; ++k) {
            knn_w[(size_t)i * K_NN + k] = e[k] * inv;
            knn_idx[(size_t)i * K_NN + k] = ids[k];
        }
        return;
    }
    // ---- LN role: one wave per row, shfl reductions, no barriers ----
    int wave = threadIdx.x >> 6;
    int lane = threadIdx.x & 63;
    long row = (long)(blockIdx.x - KNN_BLOCKS) * 4 + wave;
    const float* xr = x + row * XCOLS;

    float v[16];
#pragma unroll
    for (int k = 0; k < 16; ++k) v[k] = xr[lane + 64 * k];
    float sum = 0.f;
#pragma unroll
    for (int k = 0; k < 16; ++k) sum += v[k];
#pragma unroll
    for (int off = 32; off; off >>= 1) sum += __shfl_xor(sum, off);
    float mean = sum * (1.f / DV_DIM);
    float vs = 0.f;
#pragma unroll
    for (int k = 0; k < 16; ++k) { float d = v[k] - mean; vs += d * d; }
#pragma unroll
    for (int off = 32; off; off >>= 1) vs += __shfl_xor(vs, off);
    float rs = rsqrtf(vs * (1.f / DV_DIM) + LN_EPS_F);
#pragma unroll
    for (int k = 0; k < 16; ++k) {
        int j = lane + 64 * k;
        float y = (v[k] - mean) * rs * gv[j] + bv[j];
        xvh[row * DV_DIM + j] = bf16r(y);
    }

    float u[12];
#pragma unroll
    for (int k = 0; k < 12; ++k) u[k] = xr[DV_DIM + lane + 64 * k];
    sum = 0.f;
#pragma unroll
    for (int k = 0; k < 12; ++k) sum += u[k];
#pragma unroll
    for (int off = 32; off; off >>= 1) sum += __shfl_xor(sum, off);
    mean = sum * (1.f / DT_DIM);
    vs = 0.f;
#pragma unroll
    for (int k = 0; k < 12; ++k) { float d = u[k] - mean; vs += d * d; }
#pragma unroll
    for (int off = 32; off; off >>= 1) vs += __shfl_xor(vs, off);
    rs = rsqrtf(vs * (1.f / DT_DIM) + LN_EPS_F);
#pragma unroll
    for (int k = 0; k < 12; ++k) {
        int j = lane + 64 * k;
        float y = (u[k] - mean) * rs * gt[j] + bt[j];
        xth[row * DT_DIM + j] = bf16r(y);
    }
}

// ---------------- XCD swizzle helper ----------------
__device__ inline int xcd_swz(int wg, int nwg) {
    int q = nwg >> 3, r = nwg & 7;
    int xc = wg & 7, ii = wg >> 3;
    return (xc < r ? xc * (q + 1) : r * (q + 1) + (xc - r) * q) + ii;
}

// ---------------- generic MFMA GEMM: tile 64 x (32*NF), 4 waves 2x2, BK=64 ----------------
// MODE 3: Ch = bf16(relu(acc+bias))
// MODE 4: Ch = bf16(acc+bias)
// MODE 5: Ch = bf16(bf2f(auxh)*gate + 0.5*(acc+bias))
struct GemmPair {
    const short* Ah;
    const short* Bh;
    const float* bias;
    int K; int ncb; int colOff;
};

template <int MODE, int NF>
__global__ __launch_bounds__(256) void gemm2_kernel(
    GemmPair P0, GemmPair P1, int nblk0,
    short* __restrict__ Ch, int ldc,
    const short* __restrict__ auxh, const float* __restrict__ gpv) {
    constexpr int ASZ = 4096;
    constexpr int BSZ = 32 * NF * 64;
    __shared__ short lds[ASZ + BSZ];
    short* sAh = lds;
    short* sBh = lds + ASZ;

    const int tid = threadIdx.x;
    const int lane = tid & 63;
    const int wave = tid >> 6;
    const int wm = wave >> 1, wn = wave & 1;
    const int l15 = lane & 15, lq = lane >> 4;

    int wid = xcd_swz(blockIdx.x, gridDim.x);
    GemmPair G = P0;
    if (wid >= nblk0) { G = P1; wid -= nblk0; }

    const int panel = wid / G.ncb, cb = wid - panel * G.ncb;
    const long rowBase = (long)panel * 64;
    const int colBase = cb * (32 * NF);
    const int K = G.K;

    f32x4 acc[2][NF];
#pragma unroll
    for (int i = 0; i < 2; ++i)
#pragma unroll
        for (int j = 0; j < NF; ++j) acc[i][j] = (f32x4){0.f, 0.f, 0.f, 0.f};

    short8v pAh[2], pBh[NF];
    const int ar0 = tid >> 3, ac = tid & 7;
    const int ar1 = (tid + 256) >> 3;

    {
        long go0 = (rowBase + ar0) * K + ac * 8;
        long go1 = (rowBase + ar1) * K + ac * 8;
        pAh[0] = *(const short8v*)(G.Ah + go0);
        pAh[1] = *(const short8v*)(G.Ah + go1);
#pragma unroll
        for (int j = 0; j < NF; ++j) {
            int cid = tid + 256 * j;
            int cl = cid >> 3, c = cid & 7;
            long go = (colBase + cl) * (long)K + c * 8;
            pBh[j] = *(const short8v*)(G.Bh + go);
        }
    }

    const int nsteps = K >> 6;
    for (int s = 0; s < nsteps; ++s) {
        __syncthreads();
        {
            int off0 = ar0 * 64 + ((ac ^ (ar0 & 7)) << 3);
            int off1 = ar1 * 64 + ((ac ^ (ar1 & 7)) << 3);
            *(short8v*)(sAh + off0) = pAh[0];
            *(short8v*)(sAh + off1) = pAh[1];
#pragma unroll
            for (int j = 0; j < NF; ++j) {
                int cid = tid + 256 * j;
                int cl = cid >> 3, c = cid & 7;
                int off = cl * 64 + ((c ^ (cl & 7)) << 3);
                *(short8v*)(sBh + off) = pBh[j];
            }
        }
        __syncthreads();
        if (s + 1 < nsteps) {
            long ko = (long)(s + 1) * 64;
            long go0 = (rowBase + ar0) * K + ko + ac * 8;
            long go1 = (rowBase + ar1) * K + ko + ac * 8;
            pAh[0] = *(const short8v*)(G.Ah + go0);
            pAh[1] = *(const short8v*)(G.Ah + go1);
#pragma unroll
            for (int j = 0; j < NF; ++j) {
                int cid = tid + 256 * j;
                int cl = cid >> 3, c = cid & 7;
                long go = (colBase + cl) * (long)K + ko + c * 8;
                pBh[j] = *(const short8v*)(G.Bh + go);
            }
        }
#pragma unroll
        for (int ksub = 0; ksub < 2; ++ksub) {
            int cc = ksub * 4 + lq;
            short8v afh[2], bfh[NF];
#pragma unroll
            for (int mf = 0; mf < 2; ++mf) {
                int rr = wm * 32 + mf * 16 + l15;
                int off = rr * 64 + ((cc ^ (rr & 7)) << 3);
                afh[mf] = *(short8v*)(sAh + off);
            }
#pragma unroll
            for (int nf = 0; nf < NF; ++nf) {
                int cl = wn * (NF * 16) + nf * 16 + l15;
                int off = cl * 64 + ((cc ^ (cl & 7)) << 3);
                bfh[nf] = *(short8v*)(sBh + off);
            }
#pragma unroll
            for (int mf = 0; mf < 2; ++mf)
#pragma unroll
                for (int nf = 0; nf < NF; ++nf)
                    acc[mf][nf] = __builtin_amdgcn_mfma_f32_16x16x32_bf16(afh[mf], bfh[nf], acc[mf][nf], 0, 0, 0);
        }
    }

#pragma unroll
    for (int mf = 0; mf < 2; ++mf)
#pragma unroll
        for (int nf = 0; nf < NF; ++nf) {
            int col = colBase + wn * (NF * 16) + nf * 16 + l15;
            long row0 = rowBase + wm * 32 + mf * 16 + lq * 4;
#pragma unroll
            for (int rr = 0; rr < 4; ++rr) {
                long row = row0 + rr;
                float v = acc[mf][nf][rr] + G.bias[col];
                long o = row * ldc + G.colOff + col;
                if (MODE == 4) {
                    Ch[o] = bf16r(v);
                } else if (MODE == 3) {
                    Ch[o] = bf16r(fmaxf(v, 0.f));
                } else {  // MODE 5
                    float g = gpv[row * 2 + (col >= H_DIM ? 1 : 0)];
                    float fv = bf2f(auxh[row * FD_DIM + col]) * g + ALPHA_F * v;
                    Ch[o] = bf16r(fv);
                }
            }
        }
}

// ---------------- post_base: class prior + gi concat + neigh_agg gather ----------------
__global__ __launch_bounds__(256) void post_base_kernel(
    const short* __restrict__ baseh, const float* __restrict__ Wcp,
    const float* __restrict__ bcp, const int* __restrict__ kidx,
    const float* __restrict__ wgt, short* __restrict__ gih,
    short* __restrict__ aggh) {
    int row = blockIdx.x;
    int t = threadIdx.x;
    short sa = baseh[(size_t)row * FD_DIM + t];
    short sb = baseh[(size_t)row * FD_DIM + t + 256];
    float a = bf2f(sa), b = bf2f(sb);

    __shared__ float red[C_CLS][256];
#pragma unroll
    for (int n = 0; n < C_CLS; ++n)
        red[n][t] = a * Wcp[t * C_CLS + n] + b * Wcp[(t + 256) * C_CLS + n];
    __syncthreads();
    for (int off = 128; off; off >>= 1) {
        if (t < off) {
#pragma unroll
            for (int n = 0; n < C_CLS; ++n) red[n][t] += red[n][t + off];
        }
        __syncthreads();
    }
    size_t go = (size_t)row * GIP_DIM;
    if (t == 0) {
        float lg[C_CLS];
#pragma unroll
        for (int n = 0; n < C_CLS; ++n) lg[n] = red[n][0] + bcp[n];
        float mx = lg[0];
#pragma unroll
        for (int n = 1; n < C_CLS; ++n) mx = fmaxf(mx, lg[n]);
        float s = 0.f;
        float e[C_CLS];
#pragma unroll
        for (int n = 0; n < C_CLS; ++n) { e[n] = expf(lg[n] - mx); s += e[n]; }
        float inv = 1.f / s;
#pragma unroll
        for (int n = 0; n < C_CLS; ++n) gih[go + FD_DIM + n] = bf16r(e[n] * inv);
    }
    gih[go + t] = sa;
    gih[go + t + 256] = sb;
    if (t < GIP_DIM - GI_REAL) gih[go + GI_REAL + t] = 0;

    int jj[K_NN];
    float ww[K_NN];
#pragma unroll
    for (int k = 0; k < K_NN; ++k) {
        jj[k] = kidx[(size_t)row * K_NN + k];
        ww[k] = wgt[(size_t)row * K_NN + k];
    }
#pragma unroll
    for (int half = 0; half < 2; ++half) {
        int d = t + half * 256;
        float s = 0.f;
#pragma unroll
        for (int k = 0; k < K_NN; ++k)
            s = fmaf(ww[k], bf2f(baseh[(size_t)jj[k] * FD_DIM + d]), s);
        aggh[(size_t)row * FD_DIM + d] = bf16r(s);
    }
}

// ---------------- gated gather (spatial update input) ----------------
__global__ __launch_bounds__(256) void gather_gate_kernel(
    const short* __restrict__ baseh, const int* __restrict__ kidx,
    const float* __restrict__ wgt, const float* __restrict__ gp,
    short* __restrict__ oh) {
    int row = blockIdx.x;
    int t = threadIdx.x;
    int jj[K_NN];
    float ww[K_NN], g0[K_NN], g1[K_NN];
#pragma unroll
    for (int k = 0; k < K_NN; ++k) {
        jj[k] = kidx[(size_t)row * K_NN + k];
        ww[k] = wgt[(size_t)row * K_NN + k];
        g0[k] = gp[(size_t)jj[k] * 2 + 0];
        g1[k] = gp[(size_t)jj[k] * 2 + 1];
    }
#pragma unroll
    for (int half = 0; half < 2; ++half) {
        int d = t + half * 256;
        float s = 0.f;
#pragma unroll
        for (int k = 0; k < K_NN; ++k) {
            float f = bf2f(baseh[(size_t)jj[k] * FD_DIM + d]);
            f *= (d < H_DIM) ? g0[k] : g1[k];
            s = fmaf(ww[k], f, s);
        }
        oh[(size_t)row * FD_DIM + d] = bf16r(s);
    }
}

// ---------------- fused ctx1+ctx2: 32-row slab, N=256 full ----------------
__global__ __launch_bounds__(256) void ctxfused_kernel(
    const short* __restrict__ aggh, const short* __restrict__ wx1, const float* __restrict__ b1,
    const short* __restrict__ wx2, const float* __restrict__ b2, short* __restrict__ gih) {
    __shared__ short lds[2048 + 16384 + 8192];
    short* sA = lds;
    short* sB = lds + 2048;
    short* sH = lds + 2048 + 16384;

    const int tid = threadIdx.x;
    const int lane = tid & 63;
    const int wave = tid >> 6;
    const int l15 = lane & 15, lq = lane >> 4;
    int panel = xcd_swz(blockIdx.x, gridDim.x);
    const long rowBase = (long)panel * 32;

    const int ar = tid >> 3, ac = tid & 7;

    f32x4 acc[2][4];
#pragma unroll
    for (int i = 0; i < 2; ++i)
#pragma unroll
        for (int j = 0; j < 4; ++j) acc[i][j] = (f32x4){0.f, 0.f, 0.f, 0.f};

    short8v pA, pB[8];
    {
        pA = *(const short8v*)(aggh + (rowBase + ar) * 512 + ac * 8);
#pragma unroll
        for (int j = 0; j < 8; ++j) {
            int cid = tid + 256 * j;
            int cl = cid >> 3, c = cid & 7;
            pB[j] = *(const short8v*)(wx1 + (long)cl * 512 + c * 8);
        }
    }
    for (int s = 0; s < 8; ++s) {
        __syncthreads();
        *(short8v*)(sA + ar * 64 + ((ac ^ (ar & 7)) << 3)) = pA;
#pragma unroll
        for (int j = 0; j < 8; ++j) {
            int cid = tid + 256 * j;
            int cl = cid >> 3, c = cid & 7;
            *(short8v*)(sB + cl * 64 + ((c ^ (cl & 7)) << 3)) = pB[j];
        }
        __syncthreads();
        if (s + 1 < 8) {
            long ko = (long)(s + 1) * 64;
            pA = *(const short8v*)(aggh + (rowBase + ar) * 512 + ko + ac * 8);
#pragma unroll
            for (int j = 0; j < 8; ++j) {
                int cid = tid + 256 * j;
                int cl = cid >> 3, c = cid & 7;
                pB[j] = *(const short8v*)(wx1 + (long)cl * 512 + ko + c * 8);
            }
        }
#pragma unroll
        for (int ksub = 0; ksub < 2; ++ksub) {
            int cc = ksub * 4 + lq;
            short8v af[2], bf[4];
#pragma unroll
            for (int mf = 0; mf < 2; ++mf) {
                int rr = mf * 16 + l15;
                af[mf] = *(short8v*)(sA + rr * 64 + ((cc ^ (rr & 7)) << 3));
            }
#pragma unroll
            for (int nf = 0; nf < 4; ++nf) {
                int cl = wave * 64 + nf * 16 + l15;
                bf[nf] = *(short8v*)(sB + cl * 64 + ((cc ^ (cl & 7)) << 3));
            }
#pragma unroll
            for (int mf = 0; mf < 2; ++mf)
#pragma unroll
                for (int nf = 0; nf < 4; ++nf)
                    acc[mf][nf] = __builtin_amdgcn_mfma_f32_16x16x32_bf16(af[mf], bf[nf], acc[mf][nf], 0, 0, 0);
        }
    }
    __syncthreads();
#pragma unroll
    for (int mf = 0; mf < 2; ++mf)
#pragma unroll
        for (int nf = 0; nf < 4; ++nf) {
            int col = wave * 64 + nf * 16 + l15;
            int sub = col >> 6, cch = (col >> 3) & 7, ce = col & 7;
#pragma unroll
            for (int rr = 0; rr < 4; ++rr) {
                int r = mf * 16 + lq * 4 + rr;
                float v = fmaxf(acc[mf][nf][rr] + b1[col], 0.f);
                sH[sub * 2048 + r * 64 + ((cch ^ (r & 7)) << 3) + ce] = bf16r(v);
            }
        }
    f32x4 acc2[2][4];
#pragma unroll
    for (int i = 0; i < 2; ++i)
#pragma unroll
        for (int j = 0; j < 4; ++j) acc2[i][j] = (f32x4){0.f, 0.f, 0.f, 0.f};
    for (int s = 0; s < 4; ++s) {
        __syncthreads();
#pragma unroll
        for (int j = 0; j < 8; ++j) {
            int cid = tid + 256 * j;
            int cl = cid >> 3, c = cid & 7;
            short8v b = *(const short8v*)(wx2 + (long)cl * 256 + s * 64 + c * 8);
            *(short8v*)(sB + cl * 64 + ((c ^ (cl & 7)) << 3)) = b;
        }
        __syncthreads();
#pragma unroll
        for (int ksub = 0; ksub < 2; ++ksub) {
            int cc = ksub * 4 + lq;
            short8v af[2], bf[4];
#pragma unroll
            for (int mf = 0; mf < 2; ++mf) {
                int rr = mf * 16 + l15;
                af[mf] = *(short8v*)(sH + s * 2048 + rr * 64 + ((cc ^ (rr & 7)) << 3));
            }
#pragma unroll
            for (int nf = 0; nf < 4; ++nf) {
                int cl = wave * 64 + nf * 16 + l15;
                bf[nf] = *(short8v*)(sB + cl * 64 + ((cc ^ (cl & 7)) << 3));
            }
#pragma unroll
            for (int mf = 0; mf < 2; ++mf)
#pragma unroll
                for (int nf = 0; nf < 4; ++nf)
                    acc2[mf][nf] = __builtin_amdgcn_mfma_f32_16x16x32_bf16(af[mf], bf[nf], acc2[mf][nf], 0, 0, 0);
        }
    }
#pragma unroll
    for (int mf = 0; mf < 2; ++mf)
#pragma unroll
        for (int nf = 0; nf < 4; ++nf) {
            int col = wave * 64 + nf * 16 + l15;
#pragma unroll
            for (int rr = 0; rr < 4; ++rr) {
                long row = rowBase + mf * 16 + lq * 4 + rr;
                gih[row * GIP_DIM + FD_DIM + C_CLS + col] = bf16r(acc2[mf][nf][rr] + b2[col]);
            }
        }
}

// ---------------- fused g1 + gate head: 64x128 block, K=832 ----------------
__global__ __launch_bounds__(256) void g1gate_kernel(
    const short* __restrict__ gih, const short* __restrict__ wg1, const float* __restrict__ b1,
    const float* __restrict__ W2, const float* __restrict__ b2,
    float* __restrict__ gp, float* __restrict__ entpart) {
    __shared__ float hls[64 * 128];
    short* sA = (short*)hls;
    short* sB = sA + 4096;
    __shared__ float entrow[64];

    const int tid = threadIdx.x;
    const int lane = tid & 63;
    const int wave = tid >> 6;
    const int wm = wave >> 1, wn = wave & 1;
    const int l15 = lane & 15, lq = lane >> 4;
    int panel = xcd_swz(blockIdx.x, gridDim.x);
    const long rowBase = (long)panel * 64;

    const int ar0 = tid >> 3, ac = tid & 7;
    const int ar1 = (tid + 256) >> 3;
    constexpr int K = GIP_DIM;

    f32x4 acc[2][4];
#pragma unroll
    for (int i = 0; i < 2; ++i)
#pragma unroll
        for (int j = 0; j < 4; ++j) acc[i][j] = (f32x4){0.f, 0.f, 0.f, 0.f};

    short8v pA0, pA1, pB[4];
    {
        pA0 = *(const short8v*)(gih + (rowBase + ar0) * K + ac * 8);
        pA1 = *(const short8v*)(gih + (rowBase + ar1) * K + ac * 8);
#pragma unroll
        for (int j = 0; j < 4; ++j) {
            int cid = tid + 256 * j;
            int cl = cid >> 3, c = cid & 7;
            pB[j] = *(const short8v*)(wg1 + (long)cl * K + c * 8);
        }
    }
    const int nsteps = K >> 6;  // 13
    for (int s = 0; s < nsteps; ++s) {
        __syncthreads();
        *(short8v*)(sA + ar0 * 64 + ((ac ^ (ar0 & 7)) << 3)) = pA0;
        *(short8v*)(sA + ar1 * 64 + ((ac ^ (ar1 & 7)) << 3)) = pA1;
#pragma unroll
        for (int j = 0; j < 4; ++j) {
            int cid = tid + 256 * j;
            int cl = cid >> 3, c = cid & 7;
            *(short8v*)(sB + cl * 64 + ((c ^ (cl & 7)) << 3)) = pB[j];
        }
        __syncthreads();
        if (s + 1 < nsteps) {
            long ko = (long)(s + 1) * 64;
            pA0 = *(const short8v*)(gih + (rowBase + ar0) * K + ko + ac * 8);
            pA1 = *(const short8v*)(gih + (rowBase + ar1) * K + ko + ac * 8);
#pragma unroll
            for (int j = 0; j < 4; ++j) {
                int cid = tid + 256 * j;
                int cl = cid >> 3, c = cid & 7;
                pB[j] = *(const short8v*)(wg1 + (long)cl * K + ko + c * 8);
            }
        }
#pragma unroll
        for (int ksub = 0; ksub < 2; ++ksub) {
            int cc = ksub * 4 + lq;
            short8v af[2], bf[4];
#pragma unroll
            for (int mf = 0; mf < 2; ++mf) {
                int rr = wm * 32 + mf * 16 + l15;
                af[mf] = *(short8v*)(sA + rr * 64 + ((cc ^ (rr & 7)) << 3));
            }
#pragma unroll
            for (int nf = 0; nf < 4; ++nf) {
                int cl = wn * 64 + nf * 16 + l15;
                bf[nf] = *(short8v*)(sB + cl * 64 + ((cc ^ (cl & 7)) << 3));
            }
#pragma unroll
            for (int mf = 0; mf < 2; ++mf)
#pragma unroll
                for (int nf = 0; nf < 4; ++nf)
                    acc[mf][nf] = __builtin_amdgcn_mfma_f32_16x16x32_bf16(af[mf], bf[nf], acc[mf][nf], 0, 0, 0);
        }
    }
    __syncthreads();
#pragma unroll
    for (int mf = 0; mf < 2; ++mf)
#pragma unroll
        for (int nf = 0; nf < 4; ++nf) {
            int col = wn * 64 + nf * 16 + l15;
#pragma unroll
            for (int rr = 0; rr < 4; ++rr) {
                int r = wm * 32 + mf * 16 + lq * 4 + rr;
                hls[r * 128 + col] = fmaxf(acc[mf][nf][rr] + b1[col], 0.f);
            }
        }
    __syncthreads();
    {
        int r = tid >> 2, p = tid & 3;
        float a0 = 0.f, a1 = 0.f;
#pragma unroll
        for (int i = 0; i < 32; ++i) {
            int c = p + i * 4;
            float hv = hls[r * 128 + c];
            a0 = fmaf(hv, W2[c * 2 + 0], a0);
            a1 = fmaf(hv, W2[c * 2 + 1], a1);
        }
        a0 += __shfl_xor(a0, 1); a1 += __shfl_xor(a1, 1);
        a0 += __shfl_xor(a0, 2); a1 += __shfl_xor(a1, 2);
        if (p == 0) {
            float l0 = a0 + b2[0], l1 = a1 + b2[1];
            float mx = fmaxf(l0, l1);
            float e0 = expf(l0 - mx), e1 = expf(l1 - mx);
            float ssum = e0 + e1;
            float p0 = e0 / ssum, p1 = e1 / ssum;
            long grow = rowBase + r;
            gp[grow * 2 + 0] = p0;
            gp[grow * 2 + 1] = p1;
            entrow[r] = -(p0 * logf(p0 + 1e-8f) + p1 * logf(p1 + 1e-8f));
        }
    }
    __syncthreads();
    if (tid == 0) {
        float s = 0.f;
        for (int r = 0; r < 64; ++r) s += entrow[r];
        entpart[blockIdx.x] = s;
    }
}

// ---------------- fused c1 + BN + relu + logits (+ entropy finalize) ----------------
__global__ __launch_bounds__(256) void c1logits_kernel(
    const short* __restrict__ fusedh, const short* __restrict__ wc1, const float* __restrict__ b1,
    const float* __restrict__ bng, const float* __restrict__ bnb,
    const float* __restrict__ W2, const float* __restrict__ b2,
    const float* __restrict__ entpart, float* __restrict__ out) {
    __shared__ short lds[2048 + 16384];
    short* sA = lds;
    short* sB = lds + 2048;
    float* hls = (float*)lds;

    const int tid = threadIdx.x;
    const int lane = tid & 63;
    const int wave = tid >> 6;
    const int l15 = lane & 15, lq = lane >> 4;
    int panel = xcd_swz(blockIdx.x, gridDim.x);
    const long rowBase = (long)panel * 32;
    const int ar = tid >> 3, ac = tid & 7;

    f32x4 acc[2][4];
#pragma unroll
    for (int i = 0; i < 2; ++i)
#pragma unroll
        for (int j = 0; j < 4; ++j) acc[i][j] = (f32x4){0.f, 0.f, 0.f, 0.f};

    short8v pA, pB[8];
    {
        pA = *(const short8v*)(fusedh + (rowBase + ar) * 512 + ac * 8);
#pragma unroll
        for (int j = 0; j < 8; ++j) {
            int cid = tid + 256 * j;
            int cl = cid >> 3, c = cid & 7;
            pB[j] = *(const short8v*)(wc1 + (long)cl * 512 + c * 8);
        }
    }
    for (int s = 0; s < 8; ++s) {
        __syncthreads();
        *(short8v*)(sA + ar * 64 + ((ac ^ (ar & 7)) << 3)) = pA;
#pragma unroll
        for (int j = 0; j < 8; ++j) {
            int cid = tid + 256 * j;
            int cl = cid >> 3, c = cid & 7;
            *(short8v*)(sB + cl * 64 + ((c ^ (cl & 7)) << 3)) = pB[j];
        }
        __syncthreads();
        if (s + 1 < 8) {
            long ko = (long)(s + 1) * 64;
            pA = *(const short8v*)(fusedh + (rowBase + ar) * 512 + ko + ac * 8);
#pragma unroll
            for (int j = 0; j < 8; ++j) {
                int cid = tid + 256 * j;
                int cl = cid >> 3, c = cid & 7;
                pB[j] = *(const short8v*)(wc1 + (long)cl * 512 + ko + c * 8);
            }
        }
#pragma unroll
        for (int ksub = 0; ksub < 2; ++ksub) {
            int cc = ksub * 4 + lq;
            short8v af[2], bf[4];
#pragma unroll
            for (int mf = 0; mf < 2; ++mf) {
                int rr = mf * 16 + l15;
                af[mf] = *(short8v*)(sA + rr * 64 + ((cc ^ (rr & 7)) << 3));
            }
#pragma unroll
            for (int nf = 0; nf < 4; ++nf) {
                int cl = wave * 64 + nf * 16 + l15;
                bf[nf] = *(short8v*)(sB + cl * 64 + ((cc ^ (cl & 7)) << 3));
            }
#pragma unroll
            for (int mf = 0; mf < 2; ++mf)
#pragma unroll
                for (int nf = 0; nf < 4; ++nf)
                    acc[mf][nf] = __builtin_amdgcn_mfma_f32_16x16x32_bf16(af[mf], bf[nf], acc[mf][nf], 0, 0, 0);
        }
    }
    __syncthreads();
#pragma unroll
    for (int mf = 0; mf < 2; ++mf)
#pragma unroll
        for (int nf = 0; nf < 4; ++nf) {
            int col = wave * 64 + nf * 16 + l15;
            float scale = bng[col] * rsqrtf(1.f + BN_EPS_F);
            float shift = bnb[col];
#pragma unroll
            for (int rr = 0; rr < 4; ++rr) {
                int r = mf * 16 + lq * 4 + rr;
                float v = (acc[mf][nf][rr] + b1[col]) * scale + shift;
                hls[r * 256 + col] = fmaxf(v, 0.f);
            }
        }
    __syncthreads();
    {
        int r = tid >> 3, p = tid & 7;
        float a[C_CLS];
#pragma unroll
        for (int n = 0; n < C_CLS; ++n) a[n] = 0.f;
#pragma unroll
        for (int i = 0; i < 32; ++i) {
            int c = p + i * 8;
            float hv = hls[r * 256 + c];
#pragma unroll
            for (int n = 0; n < C_CLS; ++n) a[n] = fmaf(hv, W2[c * 5 + n], a[n]);
        }
#pragma unroll
        for (int n = 0; n < C_CLS; ++n) {
            a[n] += __shfl_xor(a[n], 1);
            a[n] += __shfl_xor(a[n], 2);
            a[n] += __shfl_xor(a[n], 4);
        }
        if (p == 0) {
            long grow = rowBase + r;
#pragma unroll
            for (int n = 0; n < C_CLS; ++n) out[grow * C_CLS + n] = a[n] + b2[n];
        }
    }
    if (blockIdx.x == 0 && tid < 64) {
        float s = entpart[tid] + entpart[tid + 64];
        for (int off = 32; off; off >>= 1) s += __shfl_down(s, off);
        if (tid == 0) out[(size_t)B_ROWS * C_CLS] = s * (EW_F / (float)B_ROWS);
    }
}

extern "C" void kernel_launch(void* const* d_in, const int* in_sizes, int n_in,
                              void* d_out, int out_size, void* d_ws, size_t ws_size,
                              hipStream_t stream) {
    const float* x = (const float*)d_in[0];
    const float* ln_v_g = (const float*)d_in[1];
    const float* ln_v_b = (const float*)d_in[2];
    const float* ln_t_g = (const float*)d_in[3];
    const float* ln_t_b = (const float*)d_in[4];
    const float* W_v = (const float*)d_in[5];
    const float* b_v = (const float*)d_in[6];
    const float* W_t = (const float*)d_in[7];
    const float* b_t = (const float*)d_in[8];
    const float* W_cp = (const float*)d_in[9];
    const float* b_cp = (const float*)d_in[10];
    const float* W_ctx1 = (const float*)d_in[11];
    const float* b_ctx1 = (const float*)d_in[12];
    const float* W_ctx2 = (const float*)d_in[13];
    const float* b_ctx2 = (const float*)d_in[14];
    const float* W_g1 = (const float*)d_in[15];
    const float* b_g1 = (const float*)d_in[16];
    const float* W_g2 = (const float*)d_in[17];
    const float* b_g2 = (const float*)d_in[18];
    const float* W_gu1 = (const float*)d_in[19];
    const float* b_gu1 = (const float*)d_in[20];
    const float* W_gu2 = (const float*)d_in[21];
    const float* b_gu2 = (const float*)d_in[22];
    const float* W_c1 = (const float*)d_in[23];
    const float* b_c1 = (const float*)d_in[24];
    const float* bn_g = (const float*)d_in[25];
    const float* bn_b = (const float*)d_in[26];
    const float* W_c2 = (const float*)d_in[27];
    const float* b_c2 = (const float*)d_in[28];

    float* out = (float*)d_out;

    // ---- workspace arena ----
    char* wsb = (char*)d_ws;
    size_t off = 0;
    auto alloc = [&](size_t bytes) {
        char* p = wsb + off;
        off += (bytes + 255) & ~(size_t)255;
        return p;
    };
    short* baseh = (short*)alloc((size_t)B_ROWS * FD_DIM * 2);
    short* aggh = (short*)alloc((size_t)B_ROWS * FD_DIM * 2);  // agg / fusedh
    short* guh = (short*)alloc((size_t)B_ROWS * FD_DIM * 2);
    short* gih = (short*)alloc((size_t)B_ROWS * GIP_DIM * 2);
    float* gp = (float*)alloc((size_t)B_ROWS * 2 * 4);
    float* entpart = (float*)alloc(128 * 4);
    float* cxv = (float*)alloc((size_t)B_ROWS * 4);
    float* cyv = (float*)alloc((size_t)B_ROWS * 4);
    float* sqv = (float*)alloc((size_t)B_ROWS * 4);
    float* wgt = (float*)alloc((size_t)B_ROWS * K_NN * 4);
    int* imgi = (int*)alloc((size_t)B_ROWS * 4);
    int* cnt = (int*)alloc(N_IMG * 4);
    int* startb = (int*)alloc(N_IMG * 4);
    int* cursor = (int*)alloc(N_IMG * 4);
    int* perm = (int*)alloc((size_t)B_ROWS * 4);
    int* kidx = (int*)alloc((size_t)B_ROWS * K_NN * 4);
    short* wv_h = (short*)alloc(256 * 1024 * 2);
    short* wt_h = (short*)alloc(256 * 768 * 2);
    short* wx1_h = (short*)alloc(256 * 512 * 2);
    short* wx2_h = (short*)alloc(256 * 256 * 2);
    short* wg1_h = (short*)alloc(128 * GIP_DIM * 2);
    short* wu1_h = (short*)alloc(512 * 512 * 2);
    short* wu2_h = (short*)alloc(512 * 512 * 2);
    short* wc1_h = (short*)alloc(256 * 512 * 2);
    short* xvh = (short*)alloc((size_t)B_ROWS * DV_DIM * 2);
    short* xth = (short*)alloc((size_t)B_ROWS * DT_DIM * 2);
    short* fusedh = aggh;

    dim3 blk(256);
    dim3 gridRows((B_ROWS + 255) / 256);

    // ---- weight prep args (prep runs inside the lnknnprep mega-dispatch) ----
    PrepArgs pa;
    const float* pw[8] = {W_v, W_t, W_ctx1, W_ctx2, W_g1, W_gu1, W_gu2, W_c1};
    short* ph[8] = {wv_h, wt_h, wx1_h, wx2_h, wg1_h, wu1_h, wu2_h, wc1_h};
    int pK[8] = {1024, 768, 512, 256, GI_REAL, 512, 512, 512};
    int pN[8] = {256, 256, 256, 256, 128, 512, 512, 256};
    int pKp[8] = {1024, 768, 512, 256, GIP_DIM, 512, 512, 512};
    int total = 0;
    for (int s = 0; s < 8; ++s) {
        pa.W[s] = pw[s]; pa.h[s] = ph[s];
        pa.K[s] = pK[s]; pa.N[s] = pN[s]; pa.Kpad[s] = pKp[s];
        pa.cnt[s] = pN[s] * pKp[s];
        total += pa.cnt[s];
    }
    int prepBlocks = (total + 255) / 256;

    // ---- extract + buckets ----
    hipMemsetAsync(cnt, 0, N_IMG * sizeof(int), stream);
    extract_kernel<<<gridRows, blk, 0, stream>>>(x, cxv, cyv, sqv, imgi, cnt);
    scan_kernel<<<1, N_IMG, 0, stream>>>(cnt, startb, cursor);
    scatter_kernel<<<gridRows, blk, 0, stream>>>(imgi, cursor, perm);

    // ---- KNN top-8 + LN + weight prep, one mega dispatch ----
    lnknnprep_kernel<<<KNN_BLOCKS + LN_BLOCKS + prepBlocks, blk, 0, stream>>>(
        x, ln_v_g, ln_v_b, ln_t_g, ln_t_b, xvh, xth,
        cxv, cyv, sqv, imgi, cnt, startb, perm, kidx, wgt, pa);

    // ---- fv + ft (plain bf16, NF=2) -> baseh ----
    GemmPair fvP{xvh, wv_h, b_v, 1024, 4, 0};
    GemmPair ftP{xth, wt_h, b_t, 768, 4, 256};
    gemm2_kernel<4, 2><<<1024, blk, 0, stream>>>(fvP, ftP, 512, baseh, FD_DIM,
                                                 nullptr, nullptr);

    // ---- class prior + gi concat + neigh_agg ----
    post_base_kernel<<<B_ROWS, blk, 0, stream>>>(baseh, W_cp, b_cp, kidx, wgt, gih, aggh);

    // ---- ctx1+ctx2 fused -> gi[:, 517:773] ----
    ctxfused_kernel<<<256, blk, 0, stream>>>(aggh, wx1_h, b_ctx1, wx2_h, b_ctx2, gih);

    // ---- g1 + gate fused ----
    g1gate_kernel<<<128, blk, 0, stream>>>(gih, wg1_h, b_g1, W_g2, b_g2, gp, entpart);

    // ---- spatial update (separate u1/u2 GEMMs, 64-row panels for weight reuse) ----
    gather_gate_kernel<<<B_ROWS, blk, 0, stream>>>(baseh, kidx, wgt, gp, aggh);
    GemmPair u1P{aggh, wu1_h, b_gu1, 512, 4, 0};
    gemm2_kernel<3, 4><<<512, blk, 0, stream>>>(u1P, u1P, 512, guh, FD_DIM,
                                                nullptr, nullptr);
    GemmPair u2P{guh, wu2_h, b_gu2, 512, 4, 0};
    gemm2_kernel<5, 4><<<512, blk, 0, stream>>>(u2P, u2P, 512, fusedh, FD_DIM,
                                                baseh, gp);

    // ---- classifier head fused (+ entropy finalize) ----
    c1logits_kernel<<<256, blk, 0, stream>>>(fusedh, wc1_h, b_c1, bn_g, bn_b,
                                             W_c2, b_c2, entpart, out);

    (void)in_sizes; (void)n_in; (void)out_size; (void)ws_size;
}

// Round 14
// 169.652 us; speedup vs baseline: 1.1316x; 1.0029x over previous
//
#include <hip/hip_runtime.h>
#include <math.h>

#define B_ROWS 8192
#define DV_DIM 1024
#define DT_DIM 768
#define H_DIM 256
#define C_CLS 5
#define GH_DIM 128
#define K_NN 8
#define FD_DIM 512
#define GIP_DIM 832
#define GI_REAL 773
#define XCOLS 1797
#define NEGV -1000000000.0f
#define LN_EPS_F 1e-5f
#define BN_EPS_F 1e-5f
#define N_IMG 512
#define EW_F 0.01f
#define ALPHA_F 0.5f

typedef __attribute__((ext_vector_type(8))) short short8v;
typedef __attribute__((ext_vector_type(4))) float f32x4;

__device__ inline short bf16r(float f) {
    unsigned u = __float_as_uint(f);
    return (short)((u + 0x7fffu + ((u >> 16) & 1u)) >> 16);
}

__device__ inline float bf2f(short s) {
    return __uint_as_float(((unsigned)(unsigned short)s) << 16);
}

// ---------------- coordinate extract (feeds scan/scatter) ----------------
__global__ void extract_kernel(const float* __restrict__ x,
                               float* __restrict__ cx, float* __restrict__ cy,
                               float* __restrict__ sq, int* __restrict__ imgi,
                               int* __restrict__ cnt) {
    int i = blockIdx.x * blockDim.x + threadIdx.x;
    if (i >= B_ROWS) return;
    const float* row = x + (size_t)i * XCOLS;
    float a = row[DV_DIM + DT_DIM];
    float b = row[DV_DIM + DT_DIM + 1];
    cx[i] = a; cy[i] = b; sq[i] = a * a + b * b;
    int m = (int)row[DV_DIM + DT_DIM + 4];
    imgi[i] = m;
    atomicAdd(&cnt[m], 1);
}

// ---------------- KNN structure ----------------
__global__ void scan_kernel(const int* __restrict__ cnt, int* __restrict__ start,
                            int* __restrict__ cursor) {
    __shared__ int s[N_IMG];
    int t = threadIdx.x;
    s[t] = cnt[t];
    __syncthreads();
    for (int off = 1; off < N_IMG; off <<= 1) {
        int v = (t >= off) ? s[t - off] : 0;
        __syncthreads();
        s[t] += v;
        __syncthreads();
    }
    int st = s[t] - cnt[t];
    start[t] = st;
    cursor[t] = st;
}

__global__ void scatter_kernel(const int* __restrict__ imgi, int* __restrict__ cursor,
                               int* __restrict__ perm) {
    int i = blockIdx.x * blockDim.x + threadIdx.x;
    if (i >= B_ROWS) return;
    int pos = atomicAdd(&cursor[imgi[i]], 1);
    perm[pos] = i;
}

// ---------------- multi-role mega dispatch ----------------
#define KNN_BLOCKS 32
#define LN_BLOCKS (B_ROWS / 4)
struct PrepArgs {
    const float* W[8];
    short* h[8];
    int K[8];
    int N[8];
    int Kpad[8];
    int cnt[8];
};

__global__ __launch_bounds__(256) void lnknnprep_kernel(
    const float* __restrict__ x,
    const float* __restrict__ gv, const float* __restrict__ bv,
    const float* __restrict__ gt, const float* __restrict__ bt,
    short* __restrict__ xvh, short* __restrict__ xth,
    const float* __restrict__ cx, const float* __restrict__ cy,
    const float* __restrict__ sq, const int* __restrict__ imgi,
    const int* __restrict__ cnt, const int* __restrict__ start,
    const int* __restrict__ perm, int* __restrict__ knn_idx,
    float* __restrict__ knn_w, PrepArgs pa) {
    if (blockIdx.x >= KNN_BLOCKS + LN_BLOCKS) {
        // ---- weight prep role ----
        int idx = (blockIdx.x - KNN_BLOCKS - LN_BLOCKS) * 256 + threadIdx.x;
#pragma unroll
        for (int s = 0; s < 8; ++s) {
            if (idx < pa.cnt[s]) {
                int Kp = pa.Kpad[s];
                int n = idx / Kp, k = idx - n * Kp;
                float f = (k < pa.K[s]) ? pa.W[s][(size_t)k * pa.N[s] + n] : 0.f;
                pa.h[s][idx] = bf16r(f);
                return;
            }
            idx -= pa.cnt[s];
        }
        return;
    }
    if (blockIdx.x < KNN_BLOCKS) {
        // ---- KNN role ----
        int i = blockIdx.x * 256 + threadIdx.x;
        if (i >= B_ROWS) return;
        float xi = cx[i], yi = cy[i], si = sq[i];
        float vals[K_NN];
        int ids[K_NN];
#pragma unroll
        for (int k = 0; k < K_NN; ++k) { vals[k] = NEGV; ids[k] = i; }
        int m = imgi[i];
        int s = cnt[m];
        if (s >= 2) {
            int st = start[m];
            for (int t = 0; t < s; ++t) {
                int j = perm[st + t];
                if (j == i) continue;
                float d2 = si + sq[j] - 2.f * (xi * cx[j] + yi * cy[j]);
                d2 = fmaxf(d2, 0.f);
                float v = -sqrtf(d2);
                if (v > vals[K_NN - 1]) {
                    int p = K_NN - 1;
                    while (p > 0 && vals[p - 1] < v) {
                        vals[p] = vals[p - 1]; ids[p] = ids[p - 1]; --p;
                    }
                    vals[p] = v; ids[p] = j;
                }
            }
        } else {
            for (int j = 0; j < B_ROWS; ++j) {
                if (j == i) continue;
                float d2 = si + sq[j] - 2.f * (xi * cx[j] + yi * cy[j]);
                d2 = fmaxf(d2, 0.f);
                float v = -sqrtf(d2);
                if (v > vals[K_NN - 1]) {
                    int p = K_NN - 1;
                    while (p > 0 && vals[p - 1] < v) {
                        vals[p] = vals[p - 1]; ids[p] = ids[p - 1]; --p;
                    }
                    vals[p] = v; ids[p] = j;
                }
            }
        }
        float mx = vals[0];
        float e[K_NN];
        float sum = 0.f;
#pragma unroll
        for (int k = 0; k < K_NN; ++k) { e[k] = expf(vals[k] - mx); sum += e[k]; }
        float inv = 1.f / sum;
#pragma unroll
        for (int k = 0; k < K_NN; ++k) {
            knn_w[(size_t)i * K_NN + k] = e[k] * inv;
            knn_idx[(size_t)i * K_NN + k] = ids[k];
        }
        return;
    }
    // ---- LN role: one wave per row, shfl reductions, no barriers ----
    int wave = threadIdx.x >> 6;
    int lane = threadIdx.x & 63;
    long row = (long)(blockIdx.x - KNN_BLOCKS) * 4 + wave;
    const float* xr = x + row * XCOLS;

    float v[16];
#pragma unroll
    for (int k = 0; k < 16; ++k) v[k] = xr[lane + 64 * k];
    float sum = 0.f;
#pragma unroll
    for (int k = 0; k < 16; ++k) sum += v[k];
#pragma unroll
    for (int off = 32; off; off >>= 1) sum += __shfl_xor(sum, off);
    float mean = sum * (1.f / DV_DIM);
    float vs = 0.f;
#pragma unroll
    for (int k = 0; k < 16; ++k) { float d = v[k] - mean; vs += d * d; }
#pragma unroll
    for (int off = 32; off; off >>= 1) vs += __shfl_xor(vs, off);
    float rs = rsqrtf(vs * (1.f / DV_DIM) + LN_EPS_F);
#pragma unroll
    for (int k = 0; k < 16; ++k) {
        int j = lane + 64 * k;
        float y = (v[k] - mean) * rs * gv[j] + bv[j];
        xvh[row * DV_DIM + j] = bf16r(y);
    }

    float u[12];
#pragma unroll
    for (int k = 0; k < 12; ++k) u[k] = xr[DV_DIM + lane + 64 * k];
    sum = 0.f;
#pragma unroll
    for (int k = 0; k < 12; ++k) sum += u[k];
#pragma unroll
    for (int off = 32; off; off >>= 1) sum += __shfl_xor(sum, off);
    mean = sum * (1.f / DT_DIM);
    vs = 0.f;
#pragma unroll
    for (int k = 0; k < 12; ++k) { float d = u[k] - mean; vs += d * d; }
#pragma unroll
    for (int off = 32; off; off >>= 1) vs += __shfl_xor(vs, off);
    rs = rsqrtf(vs * (1.f / DT_DIM) + LN_EPS_F);
#pragma unroll
    for (int k = 0; k < 12; ++k) {
        int j = lane + 64 * k;
        float y = (u[k] - mean) * rs * gt[j] + bt[j];
        xth[row * DT_DIM + j] = bf16r(y);
    }
}

// ---------------- XCD swizzle helper ----------------
__device__ inline int xcd_swz(int wg, int nwg) {
    int q = nwg >> 3, r = nwg & 7;
    int xc = wg & 7, ii = wg >> 3;
    return (xc < r ? xc * (q + 1) : r * (q + 1) + (xc - r) * q) + ii;
}

// ---------------- generic MFMA GEMM: tile 64 x (32*NF), 4 waves 2x2, BK=64 ----------------
// MODE 3: Ch = bf16(relu(acc+bias))
// MODE 4: Ch = bf16(acc+bias)
// MODE 5: Ch = bf16(bf2f(auxh)*gate + 0.5*(acc+bias))
struct GemmPair {
    const short* Ah;
    const short* Bh;
    const float* bias;
    int K; int ncb; int colOff;
};

template <int MODE, int NF>
__global__ __launch_bounds__(256) void gemm2_kernel(
    GemmPair P0, GemmPair P1, int nblk0,
    short* __restrict__ Ch, int ldc,
    const short* __restrict__ auxh, const float* __restrict__ gpv) {
    constexpr int ASZ = 4096;
    constexpr int BSZ = 32 * NF * 64;
    __shared__ short lds[ASZ + BSZ];
    short* sAh = lds;
    short* sBh = lds + ASZ;

    const int tid = threadIdx.x;
    const int lane = tid & 63;
    const int wave = tid >> 6;
    const int wm = wave >> 1, wn = wave & 1;
    const int l15 = lane & 15, lq = lane >> 4;

    int wid = xcd_swz(blockIdx.x, gridDim.x);
    GemmPair G = P0;
    if (wid >= nblk0) { G = P1; wid -= nblk0; }

    const int panel = wid / G.ncb, cb = wid - panel * G.ncb;
    const long rowBase = (long)panel * 64;
    const int colBase = cb * (32 * NF);
    const int K = G.K;

    f32x4 acc[2][NF];
#pragma unroll
    for (int i = 0; i < 2; ++i)
#pragma unroll
        for (int j = 0; j < NF; ++j) acc[i][j] = (f32x4){0.f, 0.f, 0.f, 0.f};

    short8v pAh[2], pBh[NF];
    const int ar0 = tid >> 3, ac = tid & 7;
    const int ar1 = (tid + 256) >> 3;

    {
        long go0 = (rowBase + ar0) * K + ac * 8;
        long go1 = (rowBase + ar1) * K + ac * 8;
        pAh[0] = *(const short8v*)(G.Ah + go0);
        pAh[1] = *(const short8v*)(G.Ah + go1);
#pragma unroll
        for (int j = 0; j < NF; ++j) {
            int cid = tid + 256 * j;
            int cl = cid >> 3, c = cid & 7;
            long go = (colBase + cl) * (long)K + c * 8;
            pBh[j] = *(const short8v*)(G.Bh + go);
        }
    }

    const int nsteps = K >> 6;
    for (int s = 0; s < nsteps; ++s) {
        __syncthreads();
        {
            int off0 = ar0 * 64 + ((ac ^ (ar0 & 7)) << 3);
            int off1 = ar1 * 64 + ((ac ^ (ar1 & 7)) << 3);
            *(short8v*)(sAh + off0) = pAh[0];
            *(short8v*)(sAh + off1) = pAh[1];
#pragma unroll
            for (int j = 0; j < NF; ++j) {
                int cid = tid + 256 * j;
                int cl = cid >> 3, c = cid & 7;
                int off = cl * 64 + ((c ^ (cl & 7)) << 3);
                *(short8v*)(sBh + off) = pBh[j];
            }
        }
        __syncthreads();
        if (s + 1 < nsteps) {
            long ko = (long)(s + 1) * 64;
            long go0 = (rowBase + ar0) * K + ko + ac * 8;
            long go1 = (rowBase + ar1) * K + ko + ac * 8;
            pAh[0] = *(const short8v*)(G.Ah + go0);
            pAh[1] = *(const short8v*)(G.Ah + go1);
#pragma unroll
            for (int j = 0; j < NF; ++j) {
                int cid = tid + 256 * j;
                int cl = cid >> 3, c = cid & 7;
                long go = (colBase + cl) * (long)K + ko + c * 8;
                pBh[j] = *(const short8v*)(G.Bh + go);
            }
        }
#pragma unroll
        for (int ksub = 0; ksub < 2; ++ksub) {
            int cc = ksub * 4 + lq;
            short8v afh[2], bfh[NF];
#pragma unroll
            for (int mf = 0; mf < 2; ++mf) {
                int rr = wm * 32 + mf * 16 + l15;
                int off = rr * 64 + ((cc ^ (rr & 7)) << 3);
                afh[mf] = *(short8v*)(sAh + off);
            }
#pragma unroll
            for (int nf = 0; nf < NF; ++nf) {
                int cl = wn * (NF * 16) + nf * 16 + l15;
                int off = cl * 64 + ((cc ^ (cl & 7)) << 3);
                bfh[nf] = *(short8v*)(sBh + off);
            }
#pragma unroll
            for (int mf = 0; mf < 2; ++mf)
#pragma unroll
                for (int nf = 0; nf < NF; ++nf)
                    acc[mf][nf] = __builtin_amdgcn_mfma_f32_16x16x32_bf16(afh[mf], bfh[nf], acc[mf][nf], 0, 0, 0);
        }
    }

#pragma unroll
    for (int mf = 0; mf < 2; ++mf)
#pragma unroll
        for (int nf = 0; nf < NF; ++nf) {
            int col = colBase + wn * (NF * 16) + nf * 16 + l15;
            long row0 = rowBase + wm * 32 + mf * 16 + lq * 4;
#pragma unroll
            for (int rr = 0; rr < 4; ++rr) {
                long row = row0 + rr;
                float v = acc[mf][nf][rr] + G.bias[col];
                long o = row * ldc + G.colOff + col;
                if (MODE == 4) {
                    Ch[o] = bf16r(v);
                } else if (MODE == 3) {
                    Ch[o] = bf16r(fmaxf(v, 0.f));
                } else {  // MODE 5
                    float g = gpv[row * 2 + (col >= H_DIM ? 1 : 0)];
                    float fv = bf2f(auxh[row * FD_DIM + col]) * g + ALPHA_F * v;
                    Ch[o] = bf16r(fv);
                }
            }
        }
}

// ---------------- post_base: class prior + gi concat + neigh_agg gather ----------------
__global__ __launch_bounds__(256) void post_base_kernel(
    const short* __restrict__ baseh, const float* __restrict__ Wcp,
    const float* __restrict__ bcp, const int* __restrict__ kidx,
    const float* __restrict__ wgt, short* __restrict__ gih,
    short* __restrict__ aggh) {
    int row = blockIdx.x;
    int t = threadIdx.x;
    short sa = baseh[(size_t)row * FD_DIM + t];
    short sb = baseh[(size_t)row * FD_DIM + t + 256];
    float a = bf2f(sa), b = bf2f(sb);

    __shared__ float red[C_CLS][256];
#pragma unroll
    for (int n = 0; n < C_CLS; ++n)
        red[n][t] = a * Wcp[t * C_CLS + n] + b * Wcp[(t + 256) * C_CLS + n];
    __syncthreads();
    for (int off = 128; off; off >>= 1) {
        if (t < off) {
#pragma unroll
            for (int n = 0; n < C_CLS; ++n) red[n][t] += red[n][t + off];
        }
        __syncthreads();
    }
    size_t go = (size_t)row * GIP_DIM;
    if (t == 0) {
        float lg[C_CLS];
#pragma unroll
        for (int n = 0; n < C_CLS; ++n) lg[n] = red[n][0] + bcp[n];
        float mx = lg[0];
#pragma unroll
        for (int n = 1; n < C_CLS; ++n) mx = fmaxf(mx, lg[n]);
        float s = 0.f;
        float e[C_CLS];
#pragma unroll
        for (int n = 0; n < C_CLS; ++n) { e[n] = expf(lg[n] - mx); s += e[n]; }
        float inv = 1.f / s;
#pragma unroll
        for (int n = 0; n < C_CLS; ++n) gih[go + FD_DIM + n] = bf16r(e[n] * inv);
    }
    gih[go + t] = sa;
    gih[go + t + 256] = sb;
    if (t < GIP_DIM - GI_REAL) gih[go + GI_REAL + t] = 0;

    int jj[K_NN];
    float ww[K_NN];
#pragma unroll
    for (int k = 0; k < K_NN; ++k) {
        jj[k] = kidx[(size_t)row * K_NN + k];
        ww[k] = wgt[(size_t)row * K_NN + k];
    }
#pragma unroll
    for (int half = 0; half < 2; ++half) {
        int d = t + half * 256;
        float s = 0.f;
#pragma unroll
        for (int k = 0; k < K_NN; ++k)
            s = fmaf(ww[k], bf2f(baseh[(size_t)jj[k] * FD_DIM + d]), s);
        aggh[(size_t)row * FD_DIM + d] = bf16r(s);
    }
}

// ---------------- gated gather (spatial update input) ----------------
__global__ __launch_bounds__(256) void gather_gate_kernel(
    const short* __restrict__ baseh, const int* __restrict__ kidx,
    const float* __restrict__ wgt, const float* __restrict__ gp,
    short* __restrict__ oh) {
    int row = blockIdx.x;
    int t = threadIdx.x;
    int jj[K_NN];
    float ww[K_NN], g0[K_NN], g1[K_NN];
#pragma unroll
    for (int k = 0; k < K_NN; ++k) {
        jj[k] = kidx[(size_t)row * K_NN + k];
        ww[k] = wgt[(size_t)row * K_NN + k];
        g0[k] = gp[(size_t)jj[k] * 2 + 0];
        g1[k] = gp[(size_t)jj[k] * 2 + 1];
    }
#pragma unroll
    for (int half = 0; half < 2; ++half) {
        int d = t + half * 256;
        float s = 0.f;
#pragma unroll
        for (int k = 0; k < K_NN; ++k) {
            float f = bf2f(baseh[(size_t)jj[k] * FD_DIM + d]);
            f *= (d < H_DIM) ? g0[k] : g1[k];
            s = fmaf(ww[k], f, s);
        }
        oh[(size_t)row * FD_DIM + d] = bf16r(s);
    }
}

// ---------------- fused ctx1+ctx2: 32-row slab, N=256 full ----------------
__global__ __launch_bounds__(256) void ctxfused_kernel(
    const short* __restrict__ aggh, const short* __restrict__ wx1, const float* __restrict__ b1,
    const short* __restrict__ wx2, const float* __restrict__ b2, short* __restrict__ gih) {
    __shared__ short lds[2048 + 16384 + 8192];
    short* sA = lds;
    short* sB = lds + 2048;
    short* sH = lds + 2048 + 16384;

    const int tid = threadIdx.x;
    const int lane = tid & 63;
    const int wave = tid >> 6;
    const int l15 = lane & 15, lq = lane >> 4;
    int panel = xcd_swz(blockIdx.x, gridDim.x);
    const long rowBase = (long)panel * 32;

    const int ar = tid >> 3, ac = tid & 7;

    f32x4 acc[2][4];
#pragma unroll
    for (int i = 0; i < 2; ++i)
#pragma unroll
        for (int j = 0; j < 4; ++j) acc[i][j] = (f32x4){0.f, 0.f, 0.f, 0.f};

    short8v pA, pB[8];
    {
        pA = *(const short8v*)(aggh + (rowBase + ar) * 512 + ac * 8);
#pragma unroll
        for (int j = 0; j < 8; ++j) {
            int cid = tid + 256 * j;
            int cl = cid >> 3, c = cid & 7;
            pB[j] = *(const short8v*)(wx1 + (long)cl * 512 + c * 8);
        }
    }
    for (int s = 0; s < 8; ++s) {
        __syncthreads();
        *(short8v*)(sA + ar * 64 + ((ac ^ (ar & 7)) << 3)) = pA;
#pragma unroll
        for (int j = 0; j < 8; ++j) {
            int cid = tid + 256 * j;
            int cl = cid >> 3, c = cid & 7;
            *(short8v*)(sB + cl * 64 + ((c ^ (cl & 7)) << 3)) = pB[j];
        }
        __syncthreads();
        if (s + 1 < 8) {
            long ko = (long)(s + 1) * 64;
            pA = *(const short8v*)(aggh + (rowBase + ar) * 512 + ko + ac * 8);
#pragma unroll
            for (int j = 0; j < 8; ++j) {
                int cid = tid + 256 * j;
                int cl = cid >> 3, c = cid & 7;
                pB[j] = *(const short8v*)(wx1 + (long)cl * 512 + ko + c * 8);
            }
        }
#pragma unroll
        for (int ksub = 0; ksub < 2; ++ksub) {
            int cc = ksub * 4 + lq;
            short8v af[2], bf[4];
#pragma unroll
            for (int mf = 0; mf < 2; ++mf) {
                int rr = mf * 16 + l15;
                af[mf] = *(short8v*)(sA + rr * 64 + ((cc ^ (rr & 7)) << 3));
            }
#pragma unroll
            for (int nf = 0; nf < 4; ++nf) {
                int cl = wave * 64 + nf * 16 + l15;
                bf[nf] = *(short8v*)(sB + cl * 64 + ((cc ^ (cl & 7)) << 3));
            }
#pragma unroll
            for (int mf = 0; mf < 2; ++mf)
#pragma unroll
                for (int nf = 0; nf < 4; ++nf)
                    acc[mf][nf] = __builtin_amdgcn_mfma_f32_16x16x32_bf16(af[mf], bf[nf], acc[mf][nf], 0, 0, 0);
        }
    }
    __syncthreads();
#pragma unroll
    for (int mf = 0; mf < 2; ++mf)
#pragma unroll
        for (int nf = 0; nf < 4; ++nf) {
            int col = wave * 64 + nf * 16 + l15;
            int sub = col >> 6, cch = (col >> 3) & 7, ce = col & 7;
#pragma unroll
            for (int rr = 0; rr < 4; ++rr) {
                int r = mf * 16 + lq * 4 + rr;
                float v = fmaxf(acc[mf][nf][rr] + b1[col], 0.f);
                sH[sub * 2048 + r * 64 + ((cch ^ (r & 7)) << 3) + ce] = bf16r(v);
            }
        }
    f32x4 acc2[2][4];
#pragma unroll
    for (int i = 0; i < 2; ++i)
#pragma unroll
        for (int j = 0; j < 4; ++j) acc2[i][j] = (f32x4){0.f, 0.f, 0.f, 0.f};
    for (int s = 0; s < 4; ++s) {
        __syncthreads();
#pragma unroll
        for (int j = 0; j < 8; ++j) {
            int cid = tid + 256 * j;
            int cl = cid >> 3, c = cid & 7;
            short8v b = *(const short8v*)(wx2 + (long)cl * 256 + s * 64 + c * 8);
            *(short8v*)(sB + cl * 64 + ((c ^ (cl & 7)) << 3)) = b;
        }
        __syncthreads();
#pragma unroll
        for (int ksub = 0; ksub < 2; ++ksub) {
            int cc = ksub * 4 + lq;
            short8v af[2], bf[4];
#pragma unroll
            for (int mf = 0; mf < 2; ++mf) {
                int rr = mf * 16 + l15;
                af[mf] = *(short8v*)(sH + s * 2048 + rr * 64 + ((cc ^ (rr & 7)) << 3));
            }
#pragma unroll
            for (int nf = 0; nf < 4; ++nf) {
                int cl = wave * 64 + nf * 16 + l15;
                bf[nf] = *(short8v*)(sB + cl * 64 + ((cc ^ (cl & 7)) << 3));
            }
#pragma unroll
            for (int mf = 0; mf < 2; ++mf)
#pragma unroll
                for (int nf = 0; nf < 4; ++nf)
                    acc2[mf][nf] = __builtin_amdgcn_mfma_f32_16x16x32_bf16(af[mf], bf[nf], acc2[mf][nf], 0, 0, 0);
        }
    }
#pragma unroll
    for (int mf = 0; mf < 2; ++mf)
#pragma unroll
        for (int nf = 0; nf < 4; ++nf) {
            int col = wave * 64 + nf * 16 + l15;
#pragma unroll
            for (int rr = 0; rr < 4; ++rr) {
                long row = rowBase + mf * 16 + lq * 4 + rr;
                gih[row * GIP_DIM + FD_DIM + C_CLS + col] = bf16r(acc2[mf][nf][rr] + b2[col]);
            }
        }
}

// ---------------- fused g1 + gate head: 32x128 panels (256 blocks), K=832 ----------------
__global__ __launch_bounds__(256) void g1gate_kernel(
    const short* __restrict__ gih, const short* __restrict__ wg1, const float* __restrict__ b1,
    const float* __restrict__ W2, const float* __restrict__ b2,
    float* __restrict__ gp, float* __restrict__ entpart) {
    __shared__ float hls[5120];      // 20KB: staging (sA 4KB + sB 16KB); hls reuses first 16KB
    short* sA = (short*)hls;         // 2048 shorts
    short* sB = sA + 2048;           // 8192 shorts
    __shared__ float entrow[32];

    const int tid = threadIdx.x;
    const int lane = tid & 63;
    const int wave = tid >> 6;
    const int l15 = lane & 15, lq = lane >> 4;
    int panel = xcd_swz(blockIdx.x, gridDim.x);
    const long rowBase = (long)panel * 32;

    const int ar = tid >> 3, ac = tid & 7;  // 32 rows x 8 chunks
    constexpr int K = GIP_DIM;

    f32x4 acc[2][2];
#pragma unroll
    for (int i = 0; i < 2; ++i)
#pragma unroll
        for (int j = 0; j < 2; ++j) acc[i][j] = (f32x4){0.f, 0.f, 0.f, 0.f};

    short8v pA, pB[4];
    {
        pA = *(const short8v*)(gih + (rowBase + ar) * K + ac * 8);
#pragma unroll
        for (int j = 0; j < 4; ++j) {
            int cid = tid + 256 * j;
            int cl = cid >> 3, c = cid & 7;
            pB[j] = *(const short8v*)(wg1 + (long)cl * K + c * 8);
        }
    }
    const int nsteps = K >> 6;  // 13
    for (int s = 0; s < nsteps; ++s) {
        __syncthreads();
        *(short8v*)(sA + ar * 64 + ((ac ^ (ar & 7)) << 3)) = pA;
#pragma unroll
        for (int j = 0; j < 4; ++j) {
            int cid = tid + 256 * j;
            int cl = cid >> 3, c = cid & 7;
            *(short8v*)(sB + cl * 64 + ((c ^ (cl & 7)) << 3)) = pB[j];
        }
        __syncthreads();
        if (s + 1 < nsteps) {
            long ko = (long)(s + 1) * 64;
            pA = *(const short8v*)(gih + (rowBase + ar) * K + ko + ac * 8);
#pragma unroll
            for (int j = 0; j < 4; ++j) {
                int cid = tid + 256 * j;
                int cl = cid >> 3, c = cid & 7;
                pB[j] = *(const short8v*)(wg1 + (long)cl * K + ko + c * 8);
            }
        }
#pragma unroll
        for (int ksub = 0; ksub < 2; ++ksub) {
            int cc = ksub * 4 + lq;
            short8v af[2], bf[2];
#pragma unroll
            for (int mf = 0; mf < 2; ++mf) {
                int rr = mf * 16 + l15;
                af[mf] = *(short8v*)(sA + rr * 64 + ((cc ^ (rr & 7)) << 3));
            }
#pragma unroll
            for (int nf = 0; nf < 2; ++nf) {
                int cl = wave * 32 + nf * 16 + l15;
                bf[nf] = *(short8v*)(sB + cl * 64 + ((cc ^ (cl & 7)) << 3));
            }
#pragma unroll
            for (int mf = 0; mf < 2; ++mf)
#pragma unroll
                for (int nf = 0; nf < 2; ++nf)
                    acc[mf][nf] = __builtin_amdgcn_mfma_f32_16x16x32_bf16(af[mf], bf[nf], acc[mf][nf], 0, 0, 0);
        }
    }
    __syncthreads();
    // h = relu(acc + b1) -> hls[32][128] fp32
#pragma unroll
    for (int mf = 0; mf < 2; ++mf)
#pragma unroll
        for (int nf = 0; nf < 2; ++nf) {
            int col = wave * 32 + nf * 16 + l15;
#pragma unroll
            for (int rr = 0; rr < 4; ++rr) {
                int r = mf * 16 + lq * 4 + rr;
                hls[r * 128 + col] = fmaxf(acc[mf][nf][rr] + b1[col], 0.f);
            }
        }
    __syncthreads();
    {
        int r = tid >> 3, p = tid & 7;  // 32 rows x 8 partials
        float a0 = 0.f, a1 = 0.f;
#pragma unroll
        for (int i = 0; i < 16; ++i) {
            int c = p + i * 8;
            float hv = hls[r * 128 + c];
            a0 = fmaf(hv, W2[c * 2 + 0], a0);
            a1 = fmaf(hv, W2[c * 2 + 1], a1);
        }
        a0 += __shfl_xor(a0, 1); a1 += __shfl_xor(a1, 1);
        a0 += __shfl_xor(a0, 2); a1 += __shfl_xor(a1, 2);
        a0 += __shfl_xor(a0, 4); a1 += __shfl_xor(a1, 4);
        if (p == 0) {
            float l0 = a0 + b2[0], l1 = a1 + b2[1];
            float mx = fmaxf(l0, l1);
            float e0 = expf(l0 - mx), e1 = expf(l1 - mx);
            float ssum = e0 + e1;
            float p0 = e0 / ssum, p1 = e1 / ssum;
            long grow = rowBase + r;
            gp[grow * 2 + 0] = p0;
            gp[grow * 2 + 1] = p1;
            entrow[r] = -(p0 * logf(p0 + 1e-8f) + p1 * logf(p1 + 1e-8f));
        }
    }
    __syncthreads();
    if (tid == 0) {
        float s = 0.f;
        for (int r = 0; r < 32; ++r) s += entrow[r];
        entpart[blockIdx.x] = s;
    }
}

// ---------------- fused c1 + BN + relu + logits (+ entropy finalize) ----------------
__global__ __launch_bounds__(256) void c1logits_kernel(
    const short* __restrict__ fusedh, const short* __restrict__ wc1, const float* __restrict__ b1,
    const float* __restrict__ bng, const float* __restrict__ bnb,
    const float* __restrict__ W2, const float* __restrict__ b2,
    const float* __restrict__ entpart, float* __restrict__ out) {
    __shared__ short lds[2048 + 16384];
    short* sA = lds;
    short* sB = lds + 2048;
    float* hls = (float*)lds;

    const int tid = threadIdx.x;
    const int lane = tid & 63;
    const int wave = tid >> 6;
    const int l15 = lane & 15, lq = lane >> 4;
    int panel = xcd_swz(blockIdx.x, gridDim.x);
    const long rowBase = (long)panel * 32;
    const int ar = tid >> 3, ac = tid & 7;

    f32x4 acc[2][4];
#pragma unroll
    for (int i = 0; i < 2; ++i)
#pragma unroll
        for (int j = 0; j < 4; ++j) acc[i][j] = (f32x4){0.f, 0.f, 0.f, 0.f};

    short8v pA, pB[8];
    {
        pA = *(const short8v*)(fusedh + (rowBase + ar) * 512 + ac * 8);
#pragma unroll
        for (int j = 0; j < 8; ++j) {
            int cid = tid + 256 * j;
            int cl = cid >> 3, c = cid & 7;
            pB[j] = *(const short8v*)(wc1 + (long)cl * 512 + c * 8);
        }
    }
    for (int s = 0; s < 8; ++s) {
        __syncthreads();
        *(short8v*)(sA + ar * 64 + ((ac ^ (ar & 7)) << 3)) = pA;
#pragma unroll
        for (int j = 0; j < 8; ++j) {
            int cid = tid + 256 * j;
            int cl = cid >> 3, c = cid & 7;
            *(short8v*)(sB + cl * 64 + ((c ^ (cl & 7)) << 3)) = pB[j];
        }
        __syncthreads();
        if (s + 1 < 8) {
            long ko = (long)(s + 1) * 64;
            pA = *(const short8v*)(fusedh + (rowBase + ar) * 512 + ko + ac * 8);
#pragma unroll
            for (int j = 0; j < 8; ++j) {
                int cid = tid + 256 * j;
                int cl = cid >> 3, c = cid & 7;
                pB[j] = *(const short8v*)(wc1 + (long)cl * 512 + ko + c * 8);
            }
        }
#pragma unroll
        for (int ksub = 0; ksub < 2; ++ksub) {
            int cc = ksub * 4 + lq;
            short8v af[2], bf[4];
#pragma unroll
            for (int mf = 0; mf < 2; ++mf) {
                int rr = mf * 16 + l15;
                af[mf] = *(short8v*)(sA + rr * 64 + ((cc ^ (rr & 7)) << 3));
            }
#pragma unroll
            for (int nf = 0; nf < 4; ++nf) {
                int cl = wave * 64 + nf * 16 + l15;
                bf[nf] = *(short8v*)(sB + cl * 64 + ((cc ^ (cl & 7)) << 3));
            }
#pragma unroll
            for (int mf = 0; mf < 2; ++mf)
#pragma unroll
                for (int nf = 0; nf < 4; ++nf)
                    acc[mf][nf] = __builtin_amdgcn_mfma_f32_16x16x32_bf16(af[mf], bf[nf], acc[mf][nf], 0, 0, 0);
        }
    }
    __syncthreads();
#pragma unroll
    for (int mf = 0; mf < 2; ++mf)
#pragma unroll
        for (int nf = 0; nf < 4; ++nf) {
            int col = wave * 64 + nf * 16 + l15;
            float scale = bng[col] * rsqrtf(1.f + BN_EPS_F);
            float shift = bnb[col];
#pragma unroll
            for (int rr = 0; rr < 4; ++rr) {
                int r = mf * 16 + lq * 4 + rr;
                float v = (acc[mf][nf][rr] + b1[col]) * scale + shift;
                hls[r * 256 + col] = fmaxf(v, 0.f);
            }
        }
    __syncthreads();
    {
        int r = tid >> 3, p = tid & 7;
        float a[C_CLS];
#pragma unroll
        for (int n = 0; n < C_CLS; ++n) a[n] = 0.f;
#pragma unroll
        for (int i = 0; i < 32; ++i) {
            int c = p + i * 8;
            float hv = hls[r * 256 + c];
#pragma unroll
            for (int n = 0; n < C_CLS; ++n) a[n] = fmaf(hv, W2[c * 5 + n], a[n]);
        }
#pragma unroll
        for (int n = 0; n < C_CLS; ++n) {
            a[n] += __shfl_xor(a[n], 1);
            a[n] += __shfl_xor(a[n], 2);
            a[n] += __shfl_xor(a[n], 4);
        }
        if (p == 0) {
            long grow = rowBase + r;
#pragma unroll
            for (int n = 0; n < C_CLS; ++n) out[grow * C_CLS + n] = a[n] + b2[n];
        }
    }
    // entropy finalize (one block; entpart has 256 partials now)
    if (blockIdx.x == 0 && tid < 64) {
        float s = entpart[tid] + entpart[tid + 64] + entpart[tid + 128] + entpart[tid + 192];
        for (int off = 32; off; off >>= 1) s += __shfl_down(s, off);
        if (tid == 0) out[(size_t)B_ROWS * C_CLS] = s * (EW_F / (float)B_ROWS);
    }
}

extern "C" void kernel_launch(void* const* d_in, const int* in_sizes, int n_in,
                              void* d_out, int out_size, void* d_ws, size_t ws_size,
                              hipStream_t stream) {
    const float* x = (const float*)d_in[0];
    const float* ln_v_g = (const float*)d_in[1];
    const float* ln_v_b = (const float*)d_in[2];
    const float* ln_t_g = (const float*)d_in[3];
    const float* ln_t_b = (const float*)d_in[4];
    const float* W_v = (const float*)d_in[5];
    const float* b_v = (const float*)d_in[6];
    const float* W_t = (const float*)d_in[7];
    const float* b_t = (const float*)d_in[8];
    const float* W_cp = (const float*)d_in[9];
    const float* b_cp = (const float*)d_in[10];
    const float* W_ctx1 = (const float*)d_in[11];
    const float* b_ctx1 = (const float*)d_in[12];
    const float* W_ctx2 = (const float*)d_in[13];
    const float* b_ctx2 = (const float*)d_in[14];
    const float* W_g1 = (const float*)d_in[15];
    const float* b_g1 = (const float*)d_in[16];
    const float* W_g2 = (const float*)d_in[17];
    const float* b_g2 = (const float*)d_in[18];
    const float* W_gu1 = (const float*)d_in[19];
    const float* b_gu1 = (const float*)d_in[20];
    const float* W_gu2 = (const float*)d_in[21];
    const float* b_gu2 = (const float*)d_in[22];
    const float* W_c1 = (const float*)d_in[23];
    const float* b_c1 = (const float*)d_in[24];
    const float* bn_g = (const float*)d_in[25];
    const float* bn_b = (const float*)d_in[26];
    const float* W_c2 = (const float*)d_in[27];
    const float* b_c2 = (const float*)d_in[28];

    float* out = (float*)d_out;

    // ---- workspace arena ----
    char* wsb = (char*)d_ws;
    size_t off = 0;
    auto alloc = [&](size_t bytes) {
        char* p = wsb + off;
        off += (bytes + 255) & ~(size_t)255;
        return p;
    };
    short* baseh = (short*)alloc((size_t)B_ROWS * FD_DIM * 2);
    short* aggh = (short*)alloc((size_t)B_ROWS * FD_DIM * 2);  // agg / fusedh
    short* guh = (short*)alloc((size_t)B_ROWS * FD_DIM * 2);
    short* gih = (short*)alloc((size_t)B_ROWS * GIP_DIM * 2);
    float* gp = (float*)alloc((size_t)B_ROWS * 2 * 4);
    float* entpart = (float*)alloc(256 * 4);
    float* cxv = (float*)alloc((size_t)B_ROWS * 4);
    float* cyv = (float*)alloc((size_t)B_ROWS * 4);
    float* sqv = (float*)alloc((size_t)B_ROWS * 4);
    float* wgt = (float*)alloc((size_t)B_ROWS * K_NN * 4);
    int* imgi = (int*)alloc((size_t)B_ROWS * 4);
    int* cnt = (int*)alloc(N_IMG * 4);
    int* startb = (int*)alloc(N_IMG * 4);
    int* cursor = (int*)alloc(N_IMG * 4);
    int* perm = (int*)alloc((size_t)B_ROWS * 4);
    int* kidx = (int*)alloc((size_t)B_ROWS * K_NN * 4);
    short* wv_h = (short*)alloc(256 * 1024 * 2);
    short* wt_h = (short*)alloc(256 * 768 * 2);
    short* wx1_h = (short*)alloc(256 * 512 * 2);
    short* wx2_h = (short*)alloc(256 * 256 * 2);
    short* wg1_h = (short*)alloc(128 * GIP_DIM * 2);
    short* wu1_h = (short*)alloc(512 * 512 * 2);
    short* wu2_h = (short*)alloc(512 * 512 * 2);
    short* wc1_h = (short*)alloc(256 * 512 * 2);
    short* xvh = (short*)alloc((size_t)B_ROWS * DV_DIM * 2);
    short* xth = (short*)alloc((size_t)B_ROWS * DT_DIM * 2);
    short* fusedh = aggh;

    dim3 blk(256);
    dim3 gridRows((B_ROWS + 255) / 256);

    // ---- weight prep args (prep runs inside the lnknnprep mega-dispatch) ----
    PrepArgs pa;
    const float* pw[8] = {W_v, W_t, W_ctx1, W_ctx2, W_g1, W_gu1, W_gu2, W_c1};
    short* ph[8] = {wv_h, wt_h, wx1_h, wx2_h, wg1_h, wu1_h, wu2_h, wc1_h};
    int pK[8] = {1024, 768, 512, 256, GI_REAL, 512, 512, 512};
    int pN[8] = {256, 256, 256, 256, 128, 512, 512, 256};
    int pKp[8] = {1024, 768, 512, 256, GIP_DIM, 512, 512, 512};
    int total = 0;
    for (int s = 0; s < 8; ++s) {
        pa.W[s] = pw[s]; pa.h[s] = ph[s];
        pa.K[s] = pK[s]; pa.N[s] = pN[s]; pa.Kpad[s] = pKp[s];
        pa.cnt[s] = pN[s] * pKp[s];
        total += pa.cnt[s];
    }
    int prepBlocks = (total + 255) / 256;

    // ---- extract + buckets ----
    hipMemsetAsync(cnt, 0, N_IMG * sizeof(int), stream);
    extract_kernel<<<gridRows, blk, 0, stream>>>(x, cxv, cyv, sqv, imgi, cnt);
    scan_kernel<<<1, N_IMG, 0, stream>>>(cnt, startb, cursor);
    scatter_kernel<<<gridRows, blk, 0, stream>>>(imgi, cursor, perm);

    // ---- KNN top-8 + LN + weight prep, one mega dispatch ----
    lnknnprep_kernel<<<KNN_BLOCKS + LN_BLOCKS + prepBlocks, blk, 0, stream>>>(
        x, ln_v_g, ln_v_b, ln_t_g, ln_t_b, xvh, xth,
        cxv, cyv, sqv, imgi, cnt, startb, perm, kidx, wgt, pa);

    // ---- fv + ft (plain bf16, NF=2) -> baseh ----
    GemmPair fvP{xvh, wv_h, b_v, 1024, 4, 0};
    GemmPair ftP{xth, wt_h, b_t, 768, 4, 256};
    gemm2_kernel<4, 2><<<1024, blk, 0, stream>>>(fvP, ftP, 512, baseh, FD_DIM,
                                                 nullptr, nullptr);

    // ---- class prior + gi concat + neigh_agg ----
    post_base_kernel<<<B_ROWS, blk, 0, stream>>>(baseh, W_cp, b_cp, kidx, wgt, gih, aggh);

    // ---- ctx1+ctx2 fused -> gi[:, 517:773] ----
    ctxfused_kernel<<<256, blk, 0, stream>>>(aggh, wx1_h, b_ctx1, wx2_h, b_ctx2, gih);

    // ---- g1 + gate fused (32-row panels, 256 blocks) ----
    g1gate_kernel<<<256, blk, 0, stream>>>(gih, wg1_h, b_g1, W_g2, b_g2, gp, entpart);

    // ---- spatial update (NF=2 -> 1024 blocks each for occupancy) ----
    gather_gate_kernel<<<B_ROWS, blk, 0, stream>>>(baseh, kidx, wgt, gp, aggh);
    GemmPair u1P{aggh, wu1_h, b_gu1, 512, 8, 0};
    gemm2_kernel<3, 2><<<1024, blk, 0, stream>>>(u1P, u1P, 1024, guh, FD_DIM,
                                                 nullptr, nullptr);
    GemmPair u2P{guh, wu2_h, b_gu2, 512, 8, 0};
    gemm2_kernel<5, 2><<<1024, blk, 0, stream>>>(u2P, u2P, 1024, fusedh, FD_DIM,
                                                 baseh, gp);

    // ---- classifier head fused (+ entropy finalize) ----
    c1logits_kernel<<<256, blk, 0, stream>>>(fusedh, wc1_h, b_c1, bn_g, bn_b,
                                             W_c2, b_c2, entpart, out);

    (void)in_sizes; (void)n_in; (void)out_size; (void)ws_size;
}

// Round 15
// 168.624 us; speedup vs baseline: 1.1385x; 1.0061x over previous
//
#include <hip/hip_runtime.h>
#include <math.h>

#define B_ROWS 8192
#define DV_DIM 1024
#define DT_DIM 768
#define H_DIM 256
#define C_CLS 5
#define GH_DIM 128
#define K_NN 8
#define FD_DIM 512
#define GIP_DIM 832
#define GI_REAL 773
#define XCOLS 1797
#define NEGV -1000000000.0f
#define LN_EPS_F 1e-5f
#define BN_EPS_F 1e-5f
#define N_IMG 512
#define EW_F 0.01f
#define ALPHA_F 0.5f

typedef __attribute__((ext_vector_type(8))) short short8v;
typedef __attribute__((ext_vector_type(4))) float f32x4;

__device__ inline short bf16r(float f) {
    unsigned u = __float_as_uint(f);
    return (short)((u + 0x7fffu + ((u >> 16) & 1u)) >> 16);
}

__device__ inline float bf2f(short s) {
    return __uint_as_float(((unsigned)(unsigned short)s) << 16);
}

// ---------------- coordinate extract (feeds scan/scatter) ----------------
__global__ void extract_kernel(const float* __restrict__ x,
                               float* __restrict__ cx, float* __restrict__ cy,
                               float* __restrict__ sq, int* __restrict__ imgi,
                               int* __restrict__ cnt) {
    int i = blockIdx.x * blockDim.x + threadIdx.x;
    if (i >= B_ROWS) return;
    const float* row = x + (size_t)i * XCOLS;
    float a = row[DV_DIM + DT_DIM];
    float b = row[DV_DIM + DT_DIM + 1];
    cx[i] = a; cy[i] = b; sq[i] = a * a + b * b;
    int m = (int)row[DV_DIM + DT_DIM + 4];
    imgi[i] = m;
    atomicAdd(&cnt[m], 1);
}

// ---------------- KNN structure ----------------
__global__ void scan_kernel(const int* __restrict__ cnt, int* __restrict__ start,
                            int* __restrict__ cursor) {
    __shared__ int s[N_IMG];
    int t = threadIdx.x;
    s[t] = cnt[t];
    __syncthreads();
    for (int off = 1; off < N_IMG; off <<= 1) {
        int v = (t >= off) ? s[t - off] : 0;
        __syncthreads();
        s[t] += v;
        __syncthreads();
    }
    int st = s[t] - cnt[t];
    start[t] = st;
    cursor[t] = st;
}

__global__ void scatter_kernel(const int* __restrict__ imgi, int* __restrict__ cursor,
                               int* __restrict__ perm) {
    int i = blockIdx.x * blockDim.x + threadIdx.x;
    if (i >= B_ROWS) return;
    int pos = atomicAdd(&cursor[imgi[i]], 1);
    perm[pos] = i;
}

// ---------------- multi-role mega dispatch ----------------
#define KNN_BLOCKS 32
#define LN_BLOCKS (B_ROWS / 4)
struct PrepArgs {
    const float* W[8];
    short* h[8];
    int K[8];
    int N[8];
    int Kpad[8];
    int cnt[8];
};

__global__ __launch_bounds__(256) void lnknnprep_kernel(
    const float* __restrict__ x,
    const float* __restrict__ gv, const float* __restrict__ bv,
    const float* __restrict__ gt, const float* __restrict__ bt,
    short* __restrict__ xvh, short* __restrict__ xth,
    const float* __restrict__ cx, const float* __restrict__ cy,
    const float* __restrict__ sq, const int* __restrict__ imgi,
    const int* __restrict__ cnt, const int* __restrict__ start,
    const int* __restrict__ perm, int* __restrict__ knn_idx,
    float* __restrict__ knn_w, PrepArgs pa) {
    if (blockIdx.x >= KNN_BLOCKS + LN_BLOCKS) {
        // ---- weight prep role ----
        int idx = (blockIdx.x - KNN_BLOCKS - LN_BLOCKS) * 256 + threadIdx.x;
#pragma unroll
        for (int s = 0; s < 8; ++s) {
            if (idx < pa.cnt[s]) {
                int Kp = pa.Kpad[s];
                int n = idx / Kp, k = idx - n * Kp;
                float f = (k < pa.K[s]) ? pa.W[s][(size_t)k * pa.N[s] + n] : 0.f;
                pa.h[s][idx] = bf16r(f);
                return;
            }
            idx -= pa.cnt[s];
        }
        return;
    }
    if (blockIdx.x < KNN_BLOCKS) {
        // ---- KNN role ----
        int i = blockIdx.x * 256 + threadIdx.x;
        if (i >= B_ROWS) return;
        float xi = cx[i], yi = cy[i], si = sq[i];
        float vals[K_NN];
        int ids[K_NN];
#pragma unroll
        for (int k = 0; k < K_NN; ++k) { vals[k] = NEGV; ids[k] = i; }
        int m = imgi[i];
        int s = cnt[m];
        if (s >= 2) {
            int st = start[m];
            for (int t = 0; t < s; ++t) {
                int j = perm[st + t];
                if (j == i) continue;
                float d2 = si + sq[j] - 2.f * (xi * cx[j] + yi * cy[j]);
                d2 = fmaxf(d2, 0.f);
                float v = -sqrtf(d2);
                if (v > vals[K_NN - 1]) {
                    int p = K_NN - 1;
                    while (p > 0 && vals[p - 1] < v) {
                        vals[p] = vals[p - 1]; ids[p] = ids[p - 1]; --p;
                    }
                    vals[p] = v; ids[p] = j;
                }
            }
        } else {
            for (int j = 0; j < B_ROWS; ++j) {
                if (j == i) continue;
                float d2 = si + sq[j] - 2.f * (xi * cx[j] + yi * cy[j]);
                d2 = fmaxf(d2, 0.f);
                float v = -sqrtf(d2);
                if (v > vals[K_NN - 1]) {
                    int p = K_NN - 1;
                    while (p > 0 && vals[p - 1] < v) {
                        vals[p] = vals[p - 1]; ids[p] = ids[p - 1]; --p;
                    }
                    vals[p] = v; ids[p] = j;
                }
            }
        }
        float mx = vals[0];
        float e[K_NN];
        float sum = 0.f;
#pragma unroll
        for (int k = 0; k < K_NN; ++k) { e[k] = expf(vals[k] - mx); sum += e[k]; }
        float inv = 1.f / sum;
#pragma unroll
        for (int k = 0; k < K_NN; ++k) {
            knn_w[(size_t)i * K_NN + k] = e[k] * inv;
            knn_idx[(size_t)i * K_NN + k] = ids[k];
        }
        return;
    }
    // ---- LN role: one wave per row; ALL loads hoisted before any reduction ----
    int wave = threadIdx.x >> 6;
    int lane = threadIdx.x & 63;
    long row = (long)(blockIdx.x - KNN_BLOCKS) * 4 + wave;
    const float* xr = x + row * XCOLS;

    float v[16], u[12];
#pragma unroll
    for (int k = 0; k < 16; ++k) v[k] = xr[lane + 64 * k];
#pragma unroll
    for (int k = 0; k < 12; ++k) u[k] = xr[DV_DIM + lane + 64 * k];

    // parallel sum reductions (independent shfl chains pipeline)
    float sv = 0.f, su = 0.f;
#pragma unroll
    for (int k = 0; k < 16; ++k) sv += v[k];
#pragma unroll
    for (int k = 0; k < 12; ++k) su += u[k];
#pragma unroll
    for (int off = 32; off; off >>= 1) {
        sv += __shfl_xor(sv, off);
        su += __shfl_xor(su, off);
    }
    float mv = sv * (1.f / DV_DIM);
    float mu = su * (1.f / DT_DIM);

    float qv = 0.f, qu = 0.f;
#pragma unroll
    for (int k = 0; k < 16; ++k) { float d = v[k] - mv; qv += d * d; }
#pragma unroll
    for (int k = 0; k < 12; ++k) { float d = u[k] - mu; qu += d * d; }
#pragma unroll
    for (int off = 32; off; off >>= 1) {
        qv += __shfl_xor(qv, off);
        qu += __shfl_xor(qu, off);
    }
    float rv = rsqrtf(qv * (1.f / DV_DIM) + LN_EPS_F);
    float ru = rsqrtf(qu * (1.f / DT_DIM) + LN_EPS_F);

#pragma unroll
    for (int k = 0; k < 16; ++k) {
        int j = lane + 64 * k;
        float y = (v[k] - mv) * rv * gv[j] + bv[j];
        xvh[row * DV_DIM + j] = bf16r(y);
    }
#pragma unroll
    for (int k = 0; k < 12; ++k) {
        int j = lane + 64 * k;
        float y = (u[k] - mu) * ru * gt[j] + bt[j];
        xth[row * DT_DIM + j] = bf16r(y);
    }
}

// ---------------- XCD swizzle helper ----------------
__device__ inline int xcd_swz(int wg, int nwg) {
    int q = nwg >> 3, r = nwg & 7;
    int xc = wg & 7, ii = wg >> 3;
    return (xc < r ? xc * (q + 1) : r * (q + 1) + (xc - r) * q) + ii;
}

// ---------------- generic MFMA GEMM: tile 64 x (32*NF), 4 waves 2x2, BK=64 ----------------
// MODE 3: Ch = bf16(relu(acc+bias))
// MODE 4: Ch = bf16(acc+bias)
// MODE 5: Ch = bf16(bf2f(auxh)*gate + 0.5*(acc+bias))
struct GemmPair {
    const short* Ah;
    const short* Bh;
    const float* bias;
    int K; int ncb; int colOff;
};

template <int MODE, int NF>
__global__ __launch_bounds__(256) void gemm2_kernel(
    GemmPair P0, GemmPair P1, int nblk0,
    short* __restrict__ Ch, int ldc,
    const short* __restrict__ auxh, const float* __restrict__ gpv) {
    constexpr int ASZ = 4096;
    constexpr int BSZ = 32 * NF * 64;
    __shared__ short lds[ASZ + BSZ];
    short* sAh = lds;
    short* sBh = lds + ASZ;

    const int tid = threadIdx.x;
    const int lane = tid & 63;
    const int wave = tid >> 6;
    const int wm = wave >> 1, wn = wave & 1;
    const int l15 = lane & 15, lq = lane >> 4;

    int wid = xcd_swz(blockIdx.x, gridDim.x);
    GemmPair G = P0;
    if (wid >= nblk0) { G = P1; wid -= nblk0; }

    const int panel = wid / G.ncb, cb = wid - panel * G.ncb;
    const long rowBase = (long)panel * 64;
    const int colBase = cb * (32 * NF);
    const int K = G.K;

    f32x4 acc[2][NF];
#pragma unroll
    for (int i = 0; i < 2; ++i)
#pragma unroll
        for (int j = 0; j < NF; ++j) acc[i][j] = (f32x4){0.f, 0.f, 0.f, 0.f};

    short8v pAh[2], pBh[NF];
    const int ar0 = tid >> 3, ac = tid & 7;
    const int ar1 = (tid + 256) >> 3;

    {
        long go0 = (rowBase + ar0) * K + ac * 8;
        long go1 = (rowBase + ar1) * K + ac * 8;
        pAh[0] = *(const short8v*)(G.Ah + go0);
        pAh[1] = *(const short8v*)(G.Ah + go1);
#pragma unroll
        for (int j = 0; j < NF; ++j) {
            int cid = tid + 256 * j;
            int cl = cid >> 3, c = cid & 7;
            long go = (colBase + cl) * (long)K + c * 8;
            pBh[j] = *(const short8v*)(G.Bh + go);
        }
    }

    const int nsteps = K >> 6;
    for (int s = 0; s < nsteps; ++s) {
        __syncthreads();
        {
            int off0 = ar0 * 64 + ((ac ^ (ar0 & 7)) << 3);
            int off1 = ar1 * 64 + ((ac ^ (ar1 & 7)) << 3);
            *(short8v*)(sAh + off0) = pAh[0];
            *(short8v*)(sAh + off1) = pAh[1];
#pragma unroll
            for (int j = 0; j < NF; ++j) {
                int cid = tid + 256 * j;
                int cl = cid >> 3, c = cid & 7;
                int off = cl * 64 + ((c ^ (cl & 7)) << 3);
                *(short8v*)(sBh + off) = pBh[j];
            }
        }
        __syncthreads();
        if (s + 1 < nsteps) {
            long ko = (long)(s + 1) * 64;
            long go0 = (rowBase + ar0) * K + ko + ac * 8;
            long go1 = (rowBase + ar1) * K + ko + ac * 8;
            pAh[0] = *(const short8v*)(G.Ah + go0);
            pAh[1] = *(const short8v*)(G.Ah + go1);
#pragma unroll
            for (int j = 0; j < NF; ++j) {
                int cid = tid + 256 * j;
                int cl = cid >> 3, c = cid & 7;
                long go = (colBase + cl) * (long)K + ko + c * 8;
                pBh[j] = *(const short8v*)(G.Bh + go);
            }
        }
#pragma unroll
        for (int ksub = 0; ksub < 2; ++ksub) {
            int cc = ksub * 4 + lq;
            short8v afh[2], bfh[NF];
#pragma unroll
            for (int mf = 0; mf < 2; ++mf) {
                int rr = wm * 32 + mf * 16 + l15;
                int off = rr * 64 + ((cc ^ (rr & 7)) << 3);
                afh[mf] = *(short8v*)(sAh + off);
            }
#pragma unroll
            for (int nf = 0; nf < NF; ++nf) {
                int cl = wn * (NF * 16) + nf * 16 + l15;
                int off = cl * 64 + ((cc ^ (cl & 7)) << 3);
                bfh[nf] = *(short8v*)(sBh + off);
            }
#pragma unroll
            for (int mf = 0; mf < 2; ++mf)
#pragma unroll
                for (int nf = 0; nf < NF; ++nf)
                    acc[mf][nf] = __builtin_amdgcn_mfma_f32_16x16x32_bf16(afh[mf], bfh[nf], acc[mf][nf], 0, 0, 0);
        }
    }

#pragma unroll
    for (int mf = 0; mf < 2; ++mf)
#pragma unroll
        for (int nf = 0; nf < NF; ++nf) {
            int col = colBase + wn * (NF * 16) + nf * 16 + l15;
            long row0 = rowBase + wm * 32 + mf * 16 + lq * 4;
#pragma unroll
            for (int rr = 0; rr < 4; ++rr) {
                long row = row0 + rr;
                float v = acc[mf][nf][rr] + G.bias[col];
                long o = row * ldc + G.colOff + col;
                if (MODE == 4) {
                    Ch[o] = bf16r(v);
                } else if (MODE == 3) {
                    Ch[o] = bf16r(fmaxf(v, 0.f));
                } else {  // MODE 5
                    float g = gpv[row * 2 + (col >= H_DIM ? 1 : 0)];
                    float fv = bf2f(auxh[row * FD_DIM + col]) * g + ALPHA_F * v;
                    Ch[o] = bf16r(fv);
                }
            }
        }
}

// ---------------- post_base: class prior + gi concat + neigh_agg gather ----------------
__global__ __launch_bounds__(256) void post_base_kernel(
    const short* __restrict__ baseh, const float* __restrict__ Wcp,
    const float* __restrict__ bcp, const int* __restrict__ kidx,
    const float* __restrict__ wgt, short* __restrict__ gih,
    short* __restrict__ aggh) {
    int row = blockIdx.x;
    int t = threadIdx.x;
    short sa = baseh[(size_t)row * FD_DIM + t];
    short sb = baseh[(size_t)row * FD_DIM + t + 256];
    float a = bf2f(sa), b = bf2f(sb);

    __shared__ float red[C_CLS][256];
#pragma unroll
    for (int n = 0; n < C_CLS; ++n)
        red[n][t] = a * Wcp[t * C_CLS + n] + b * Wcp[(t + 256) * C_CLS + n];
    __syncthreads();
    for (int off = 128; off; off >>= 1) {
        if (t < off) {
#pragma unroll
            for (int n = 0; n < C_CLS; ++n) red[n][t] += red[n][t + off];
        }
        __syncthreads();
    }
    size_t go = (size_t)row * GIP_DIM;
    if (t == 0) {
        float lg[C_CLS];
#pragma unroll
        for (int n = 0; n < C_CLS; ++n) lg[n] = red[n][0] + bcp[n];
        float mx = lg[0];
#pragma unroll
        for (int n = 1; n < C_CLS; ++n) mx = fmaxf(mx, lg[n]);
        float s = 0.f;
        float e[C_CLS];
#pragma unroll
        for (int n = 0; n < C_CLS; ++n) { e[n] = expf(lg[n] - mx); s += e[n]; }
        float inv = 1.f / s;
#pragma unroll
        for (int n = 0; n < C_CLS; ++n) gih[go + FD_DIM + n] = bf16r(e[n] * inv);
    }
    gih[go + t] = sa;
    gih[go + t + 256] = sb;
    if (t < GIP_DIM - GI_REAL) gih[go + GI_REAL + t] = 0;

    int jj[K_NN];
    float ww[K_NN];
#pragma unroll
    for (int k = 0; k < K_NN; ++k) {
        jj[k] = kidx[(size_t)row * K_NN + k];
        ww[k] = wgt[(size_t)row * K_NN + k];
    }
#pragma unroll
    for (int half = 0; half < 2; ++half) {
        int d = t + half * 256;
        float s = 0.f;
#pragma unroll
        for (int k = 0; k < K_NN; ++k)
            s = fmaf(ww[k], bf2f(baseh[(size_t)jj[k] * FD_DIM + d]), s);
        aggh[(size_t)row * FD_DIM + d] = bf16r(s);
    }
}

// ---------------- gated gather (spatial update input) ----------------
__global__ __launch_bounds__(256) void gather_gate_kernel(
    const short* __restrict__ baseh, const int* __restrict__ kidx,
    const float* __restrict__ wgt, const float* __restrict__ gp,
    short* __restrict__ oh) {
    int row = blockIdx.x;
    int t = threadIdx.x;
    int jj[K_NN];
    float ww[K_NN], g0[K_NN], g1[K_NN];
#pragma unroll
    for (int k = 0; k < K_NN; ++k) {
        jj[k] = kidx[(size_t)row * K_NN + k];
        ww[k] = wgt[(size_t)row * K_NN + k];
        g0[k] = gp[(size_t)jj[k] * 2 + 0];
        g1[k] = gp[(size_t)jj[k] * 2 + 1];
    }
#pragma unroll
    for (int half = 0; half < 2; ++half) {
        int d = t + half * 256;
        float s = 0.f;
#pragma unroll
        for (int k = 0; k < K_NN; ++k) {
            float f = bf2f(baseh[(size_t)jj[k] * FD_DIM + d]);
            f *= (d < H_DIM) ? g0[k] : g1[k];
            s = fmaf(ww[k], f, s);
        }
        oh[(size_t)row * FD_DIM + d] = bf16r(s);
    }
}

// ---------------- fused ctx1+ctx2: 32-row slab, N=256 full ----------------
__global__ __launch_bounds__(256) void ctxfused_kernel(
    const short* __restrict__ aggh, const short* __restrict__ wx1, const float* __restrict__ b1,
    const short* __restrict__ wx2, const float* __restrict__ b2, short* __restrict__ gih) {
    __shared__ short lds[2048 + 16384 + 8192];
    short* sA = lds;
    short* sB = lds + 2048;
    short* sH = lds + 2048 + 16384;

    const int tid = threadIdx.x;
    const int lane = tid & 63;
    const int wave = tid >> 6;
    const int l15 = lane & 15, lq = lane >> 4;
    int panel = xcd_swz(blockIdx.x, gridDim.x);
    const long rowBase = (long)panel * 32;

    const int ar = tid >> 3, ac = tid & 7;

    f32x4 acc[2][4];
#pragma unroll
    for (int i = 0; i < 2; ++i)
#pragma unroll
        for (int j = 0; j < 4; ++j) acc[i][j] = (f32x4){0.f, 0.f, 0.f, 0.f};

    short8v pA, pB[8];
    {
        pA = *(const short8v*)(aggh + (rowBase + ar) * 512 + ac * 8);
#pragma unroll
        for (int j = 0; j < 8; ++j) {
            int cid = tid + 256 * j;
            int cl = cid >> 3, c = cid & 7;
            pB[j] = *(const short8v*)(wx1 + (long)cl * 512 + c * 8);
        }
    }
    for (int s = 0; s < 8; ++s) {
        __syncthreads();
        *(short8v*)(sA + ar * 64 + ((ac ^ (ar & 7)) << 3)) = pA;
#pragma unroll
        for (int j = 0; j < 8; ++j) {
            int cid = tid + 256 * j;
            int cl = cid >> 3, c = cid & 7;
            *(short8v*)(sB + cl * 64 + ((c ^ (cl & 7)) << 3)) = pB[j];
        }
        __syncthreads();
        if (s + 1 < 8) {
            long ko = (long)(s + 1) * 64;
            pA = *(const short8v*)(aggh + (rowBase + ar) * 512 + ko + ac * 8);
#pragma unroll
            for (int j = 0; j < 8; ++j) {
                int cid = tid + 256 * j;
                int cl = cid >> 3, c = cid & 7;
                pB[j] = *(const short8v*)(wx1 + (long)cl * 512 + ko + c * 8);
            }
        }
#pragma unroll
        for (int ksub = 0; ksub < 2; ++ksub) {
            int cc = ksub * 4 + lq;
            short8v af[2], bf[4];
#pragma unroll
            for (int mf = 0; mf < 2; ++mf) {
                int rr = mf * 16 + l15;
                af[mf] = *(short8v*)(sA + rr * 64 + ((cc ^ (rr & 7)) << 3));
            }
#pragma unroll
            for (int nf = 0; nf < 4; ++nf) {
                int cl = wave * 64 + nf * 16 + l15;
                bf[nf] = *(short8v*)(sB + cl * 64 + ((cc ^ (cl & 7)) << 3));
            }
#pragma unroll
            for (int mf = 0; mf < 2; ++mf)
#pragma unroll
                for (int nf = 0; nf < 4; ++nf)
                    acc[mf][nf] = __builtin_amdgcn_mfma_f32_16x16x32_bf16(af[mf], bf[nf], acc[mf][nf], 0, 0, 0);
        }
    }
    __syncthreads();
#pragma unroll
    for (int mf = 0; mf < 2; ++mf)
#pragma unroll
        for (int nf = 0; nf < 4; ++nf) {
            int col = wave * 64 + nf * 16 + l15;
            int sub = col >> 6, cch = (col >> 3) & 7, ce = col & 7;
#pragma unroll
            for (int rr = 0; rr < 4; ++rr) {
                int r = mf * 16 + lq * 4 + rr;
                float v = fmaxf(acc[mf][nf][rr] + b1[col], 0.f);
                sH[sub * 2048 + r * 64 + ((cch ^ (r & 7)) << 3) + ce] = bf16r(v);
            }
        }
    f32x4 acc2[2][4];
#pragma unroll
    for (int i = 0; i < 2; ++i)
#pragma unroll
        for (int j = 0; j < 4; ++j) acc2[i][j] = (f32x4){0.f, 0.f, 0.f, 0.f};
    for (int s = 0; s < 4; ++s) {
        __syncthreads();
#pragma unroll
        for (int j = 0; j < 8; ++j) {
            int cid = tid + 256 * j;
            int cl = cid >> 3, c = cid & 7;
            short8v b = *(const short8v*)(wx2 + (long)cl * 256 + s * 64 + c * 8);
            *(short8v*)(sB + cl * 64 + ((c ^ (cl & 7)) << 3)) = b;
        }
        __syncthreads();
#pragma unroll
        for (int ksub = 0; ksub < 2; ++ksub) {
            int cc = ksub * 4 + lq;
            short8v af[2], bf[4];
#pragma unroll
            for (int mf = 0; mf < 2; ++mf) {
                int rr = mf * 16 + l15;
                af[mf] = *(short8v*)(sH + s * 2048 + rr * 64 + ((cc ^ (rr & 7)) << 3));
            }
#pragma unroll
            for (int nf = 0; nf < 4; ++nf) {
                int cl = wave * 64 + nf * 16 + l15;
                bf[nf] = *(short8v*)(sB + cl * 64 + ((cc ^ (cl & 7)) << 3));
            }
#pragma unroll
            for (int mf = 0; mf < 2; ++mf)
#pragma unroll
                for (int nf = 0; nf < 4; ++nf)
                    acc2[mf][nf] = __builtin_amdgcn_mfma_f32_16x16x32_bf16(af[mf], bf[nf], acc2[mf][nf], 0, 0, 0);
        }
    }
#pragma unroll
    for (int mf = 0; mf < 2; ++mf)
#pragma unroll
        for (int nf = 0; nf < 4; ++nf) {
            int col = wave * 64 + nf * 16 + l15;
#pragma unroll
            for (int rr = 0; rr < 4; ++rr) {
                long row = rowBase + mf * 16 + lq * 4 + rr;
                gih[row * GIP_DIM + FD_DIM + C_CLS + col] = bf16r(acc2[mf][nf][rr] + b2[col]);
            }
        }
}

// ---------------- fused g1 + gate head: 32x128 panels (256 blocks), K=832 ----------------
__global__ __launch_bounds__(256) void g1gate_kernel(
    const short* __restrict__ gih, const short* __restrict__ wg1, const float* __restrict__ b1,
    const float* __restrict__ W2, const float* __restrict__ b2,
    float* __restrict__ gp, float* __restrict__ entpart) {
    __shared__ float hls[5120];
    short* sA = (short*)hls;
    short* sB = sA + 2048;
    __shared__ float entrow[32];

    const int tid = threadIdx.x;
    const int lane = tid & 63;
    const int wave = tid >> 6;
    const int l15 = lane & 15, lq = lane >> 4;
    int panel = xcd_swz(blockIdx.x, gridDim.x);
    const long rowBase = (long)panel * 32;

    const int ar = tid >> 3, ac = tid & 7;
    constexpr int K = GIP_DIM;

    f32x4 acc[2][2];
#pragma unroll
    for (int i = 0; i < 2; ++i)
#pragma unroll
        for (int j = 0; j < 2; ++j) acc[i][j] = (f32x4){0.f, 0.f, 0.f, 0.f};

    short8v pA, pB[4];
    {
        pA = *(const short8v*)(gih + (rowBase + ar) * K + ac * 8);
#pragma unroll
        for (int j = 0; j < 4; ++j) {
            int cid = tid + 256 * j;
            int cl = cid >> 3, c = cid & 7;
            pB[j] = *(const short8v*)(wg1 + (long)cl * K + c * 8);
        }
    }
    const int nsteps = K >> 6;  // 13
    for (int s = 0; s < nsteps; ++s) {
        __syncthreads();
        *(short8v*)(sA + ar * 64 + ((ac ^ (ar & 7)) << 3)) = pA;
#pragma unroll
        for (int j = 0; j < 4; ++j) {
            int cid = tid + 256 * j;
            int cl = cid >> 3, c = cid & 7;
            *(short8v*)(sB + cl * 64 + ((c ^ (cl & 7)) << 3)) = pB[j];
        }
        __syncthreads();
        if (s + 1 < nsteps) {
            long ko = (long)(s + 1) * 64;
            pA = *(const short8v*)(gih + (rowBase + ar) * K + ko + ac * 8);
#pragma unroll
            for (int j = 0; j < 4; ++j) {
                int cid = tid + 256 * j;
                int cl = cid >> 3, c = cid & 7;
                pB[j] = *(const short8v*)(wg1 + (long)cl * K + ko + c * 8);
            }
        }
#pragma unroll
        for (int ksub = 0; ksub < 2; ++ksub) {
            int cc = ksub * 4 + lq;
            short8v af[2], bf[2];
#pragma unroll
            for (int mf = 0; mf < 2; ++mf) {
                int rr = mf * 16 + l15;
                af[mf] = *(short8v*)(sA + rr * 64 + ((cc ^ (rr & 7)) << 3));
            }
#pragma unroll
            for (int nf = 0; nf < 2; ++nf) {
                int cl = wave * 32 + nf * 16 + l15;
                bf[nf] = *(short8v*)(sB + cl * 64 + ((cc ^ (cl & 7)) << 3));
            }
#pragma unroll
            for (int mf = 0; mf < 2; ++mf)
#pragma unroll
                for (int nf = 0; nf < 2; ++nf)
                    acc[mf][nf] = __builtin_amdgcn_mfma_f32_16x16x32_bf16(af[mf], bf[nf], acc[mf][nf], 0, 0, 0);
        }
    }
    __syncthreads();
#pragma unroll
    for (int mf = 0; mf < 2; ++mf)
#pragma unroll
        for (int nf = 0; nf < 2; ++nf) {
            int col = wave * 32 + nf * 16 + l15;
#pragma unroll
            for (int rr = 0; rr < 4; ++rr) {
                int r = mf * 16 + lq * 4 + rr;
                hls[r * 128 + col] = fmaxf(acc[mf][nf][rr] + b1[col], 0.f);
            }
        }
    __syncthreads();
    {
        int r = tid >> 3, p = tid & 7;
        float a0 = 0.f, a1 = 0.f;
#pragma unroll
        for (int i = 0; i < 16; ++i) {
            int c = p + i * 8;
            float hv = hls[r * 128 + c];
            a0 = fmaf(hv, W2[c * 2 + 0], a0);
            a1 = fmaf(hv, W2[c * 2 + 1], a1);
        }
        a0 += __shfl_xor(a0, 1); a1 += __shfl_xor(a1, 1);
        a0 += __shfl_xor(a0, 2); a1 += __shfl_xor(a1, 2);
        a0 += __shfl_xor(a0, 4); a1 += __shfl_xor(a1, 4);
        if (p == 0) {
            float l0 = a0 + b2[0], l1 = a1 + b2[1];
            float mx = fmaxf(l0, l1);
            float e0 = expf(l0 - mx), e1 = expf(l1 - mx);
            float ssum = e0 + e1;
            float p0 = e0 / ssum, p1 = e1 / ssum;
            long grow = rowBase + r;
            gp[grow * 2 + 0] = p0;
            gp[grow * 2 + 1] = p1;
            entrow[r] = -(p0 * logf(p0 + 1e-8f) + p1 * logf(p1 + 1e-8f));
        }
    }
    __syncthreads();
    if (tid == 0) {
        float s = 0.f;
        for (int r = 0; r < 32; ++r) s += entrow[r];
        entpart[blockIdx.x] = s;
    }
}

// ---------------- fused c1 + BN + relu + logits (+ entropy finalize) ----------------
__global__ __launch_bounds__(256) void c1logits_kernel(
    const short* __restrict__ fusedh, const short* __restrict__ wc1, const float* __restrict__ b1,
    const float* __restrict__ bng, const float* __restrict__ bnb,
    const float* __restrict__ W2, const float* __restrict__ b2,
    const float* __restrict__ entpart, float* __restrict__ out) {
    __shared__ short lds[2048 + 16384];
    short* sA = lds;
    short* sB = lds + 2048;
    float* hls = (float*)lds;

    const int tid = threadIdx.x;
    const int lane = tid & 63;
    const int wave = tid >> 6;
    const int l15 = lane & 15, lq = lane >> 4;
    int panel = xcd_swz(blockIdx.x, gridDim.x);
    const long rowBase = (long)panel * 32;
    const int ar = tid >> 3, ac = tid & 7;

    f32x4 acc[2][4];
#pragma unroll
    for (int i = 0; i < 2; ++i)
#pragma unroll
        for (int j = 0; j < 4; ++j) acc[i][j] = (f32x4){0.f, 0.f, 0.f, 0.f};

    short8v pA, pB[8];
    {
        pA = *(const short8v*)(fusedh + (rowBase + ar) * 512 + ac * 8);
#pragma unroll
        for (int j = 0; j < 8; ++j) {
            int cid = tid + 256 * j;
            int cl = cid >> 3, c = cid & 7;
            pB[j] = *(const short8v*)(wc1 + (long)cl * 512 + c * 8);
        }
    }
    for (int s = 0; s < 8; ++s) {
        __syncthreads();
        *(short8v*)(sA + ar * 64 + ((ac ^ (ar & 7)) << 3)) = pA;
#pragma unroll
        for (int j = 0; j < 8; ++j) {
            int cid = tid + 256 * j;
            int cl = cid >> 3, c = cid & 7;
            *(short8v*)(sB + cl * 64 + ((c ^ (cl & 7)) << 3)) = pB[j];
        }
        __syncthreads();
        if (s + 1 < 8) {
            long ko = (long)(s + 1) * 64;
            pA = *(const short8v*)(fusedh + (rowBase + ar) * 512 + ko + ac * 8);
#pragma unroll
            for (int j = 0; j < 8; ++j) {
                int cid = tid + 256 * j;
                int cl = cid >> 3, c = cid & 7;
                pB[j] = *(const short8v*)(wc1 + (long)cl * 512 + ko + c * 8);
            }
        }
#pragma unroll
        for (int ksub = 0; ksub < 2; ++ksub) {
            int cc = ksub * 4 + lq;
            short8v af[2], bf[4];
#pragma unroll
            for (int mf = 0; mf < 2; ++mf) {
                int rr = mf * 16 + l15;
                af[mf] = *(short8v*)(sA + rr * 64 + ((cc ^ (rr & 7)) << 3));
            }
#pragma unroll
            for (int nf = 0; nf < 4; ++nf) {
                int cl = wave * 64 + nf * 16 + l15;
                bf[nf] = *(short8v*)(sB + cl * 64 + ((cc ^ (cl & 7)) << 3));
            }
#pragma unroll
            for (int mf = 0; mf < 2; ++mf)
#pragma unroll
                for (int nf = 0; nf < 4; ++nf)
                    acc[mf][nf] = __builtin_amdgcn_mfma_f32_16x16x32_bf16(af[mf], bf[nf], acc[mf][nf], 0, 0, 0);
        }
    }
    __syncthreads();
#pragma unroll
    for (int mf = 0; mf < 2; ++mf)
#pragma unroll
        for (int nf = 0; nf < 4; ++nf) {
            int col = wave * 64 + nf * 16 + l15;
            float scale = bng[col] * rsqrtf(1.f + BN_EPS_F);
            float shift = bnb[col];
#pragma unroll
            for (int rr = 0; rr < 4; ++rr) {
                int r = mf * 16 + lq * 4 + rr;
                float v = (acc[mf][nf][rr] + b1[col]) * scale + shift;
                hls[r * 256 + col] = fmaxf(v, 0.f);
            }
        }
    __syncthreads();
    {
        int r = tid >> 3, p = tid & 7;
        float a[C_CLS];
#pragma unroll
        for (int n = 0; n < C_CLS; ++n) a[n] = 0.f;
#pragma unroll
        for (int i = 0; i < 32; ++i) {
            int c = p + i * 8;
            float hv = hls[r * 256 + c];
#pragma unroll
            for (int n = 0; n < C_CLS; ++n) a[n] = fmaf(hv, W2[c * 5 + n], a[n]);
        }
#pragma unroll
        for (int n = 0; n < C_CLS; ++n) {
            a[n] += __shfl_xor(a[n], 1);
            a[n] += __shfl_xor(a[n], 2);
            a[n] += __shfl_xor(a[n], 4);
        }
        if (p == 0) {
            long grow = rowBase + r;
#pragma unroll
            for (int n = 0; n < C_CLS; ++n) out[grow * C_CLS + n] = a[n] + b2[n];
        }
    }
    if (blockIdx.x == 0 && tid < 64) {
        float s = entpart[tid] + entpart[tid + 64] + entpart[tid + 128] + entpart[tid + 192];
        for (int off = 32; off; off >>= 1) s += __shfl_down(s, off);
        if (tid == 0) out[(size_t)B_ROWS * C_CLS] = s * (EW_F / (float)B_ROWS);
    }
}

extern "C" void kernel_launch(void* const* d_in, const int* in_sizes, int n_in,
                              void* d_out, int out_size, void* d_ws, size_t ws_size,
                              hipStream_t stream) {
    const float* x = (const float*)d_in[0];
    const float* ln_v_g = (const float*)d_in[1];
    const float* ln_v_b = (const float*)d_in[2];
    const float* ln_t_g = (const float*)d_in[3];
    const float* ln_t_b = (const float*)d_in[4];
    const float* W_v = (const float*)d_in[5];
    const float* b_v = (const float*)d_in[6];
    const float* W_t = (const float*)d_in[7];
    const float* b_t = (const float*)d_in[8];
    const float* W_cp = (const float*)d_in[9];
    const float* b_cp = (const float*)d_in[10];
    const float* W_ctx1 = (const float*)d_in[11];
    const float* b_ctx1 = (const float*)d_in[12];
    const float* W_ctx2 = (const float*)d_in[13];
    const float* b_ctx2 = (const float*)d_in[14];
    const float* W_g1 = (const float*)d_in[15];
    const float* b_g1 = (const float*)d_in[16];
    const float* W_g2 = (const float*)d_in[17];
    const float* b_g2 = (const float*)d_in[18];
    const float* W_gu1 = (const float*)d_in[19];
    const float* b_gu1 = (const float*)d_in[20];
    const float* W_gu2 = (const float*)d_in[21];
    const float* b_gu2 = (const float*)d_in[22];
    const float* W_c1 = (const float*)d_in[23];
    const float* b_c1 = (const float*)d_in[24];
    const float* bn_g = (const float*)d_in[25];
    const float* bn_b = (const float*)d_in[26];
    const float* W_c2 = (const float*)d_in[27];
    const float* b_c2 = (const float*)d_in[28];

    float* out = (float*)d_out;

    // ---- workspace arena ----
    char* wsb = (char*)d_ws;
    size_t off = 0;
    auto alloc = [&](size_t bytes) {
        char* p = wsb + off;
        off += (bytes + 255) & ~(size_t)255;
        return p;
    };
    short* baseh = (short*)alloc((size_t)B_ROWS * FD_DIM * 2);
    short* aggh = (short*)alloc((size_t)B_ROWS * FD_DIM * 2);  // agg / fusedh
    short* guh = (short*)alloc((size_t)B_ROWS * FD_DIM * 2);
    short* gih = (short*)alloc((size_t)B_ROWS * GIP_DIM * 2);
    float* gp = (float*)alloc((size_t)B_ROWS * 2 * 4);
    float* entpart = (float*)alloc(256 * 4);
    float* cxv = (float*)alloc((size_t)B_ROWS * 4);
    float* cyv = (float*)alloc((size_t)B_ROWS * 4);
    float* sqv = (float*)alloc((size_t)B_ROWS * 4);
    float* wgt = (float*)alloc((size_t)B_ROWS * K_NN * 4);
    int* imgi = (int*)alloc((size_t)B_ROWS * 4);
    int* cnt = (int*)alloc(N_IMG * 4);
    int* startb = (int*)alloc(N_IMG * 4);
    int* cursor = (int*)alloc(N_IMG * 4);
    int* perm = (int*)alloc((size_t)B_ROWS * 4);
    int* kidx = (int*)alloc((size_t)B_ROWS * K_NN * 4);
    short* wv_h = (short*)alloc(256 * 1024 * 2);
    short* wt_h = (short*)alloc(256 * 768 * 2);
    short* wx1_h = (short*)alloc(256 * 512 * 2);
    short* wx2_h = (short*)alloc(256 * 256 * 2);
    short* wg1_h = (short*)alloc(128 * GIP_DIM * 2);
    short* wu1_h = (short*)alloc(512 * 512 * 2);
    short* wu2_h = (short*)alloc(512 * 512 * 2);
    short* wc1_h = (short*)alloc(256 * 512 * 2);
    short* xvh = (short*)alloc((size_t)B_ROWS * DV_DIM * 2);
    short* xth = (short*)alloc((size_t)B_ROWS * DT_DIM * 2);
    short* fusedh = aggh;

    dim3 blk(256);
    dim3 gridRows((B_ROWS + 255) / 256);

    // ---- weight prep args (prep runs inside the lnknnprep mega-dispatch) ----
    PrepArgs pa;
    const float* pw[8] = {W_v, W_t, W_ctx1, W_ctx2, W_g1, W_gu1, W_gu2, W_c1};
    short* ph[8] = {wv_h, wt_h, wx1_h, wx2_h, wg1_h, wu1_h, wu2_h, wc1_h};
    int pK[8] = {1024, 768, 512, 256, GI_REAL, 512, 512, 512};
    int pN[8] = {256, 256, 256, 256, 128, 512, 512, 256};
    int pKp[8] = {1024, 768, 512, 256, GIP_DIM, 512, 512, 512};
    int total = 0;
    for (int s = 0; s < 8; ++s) {
        pa.W[s] = pw[s]; pa.h[s] = ph[s];
        pa.K[s] = pK[s]; pa.N[s] = pN[s]; pa.Kpad[s] = pKp[s];
        pa.cnt[s] = pN[s] * pKp[s];
        total += pa.cnt[s];
    }
    int prepBlocks = (total + 255) / 256;

    // ---- extract + buckets ----
    hipMemsetAsync(cnt, 0, N_IMG * sizeof(int), stream);
    extract_kernel<<<gridRows, blk, 0, stream>>>(x, cxv, cyv, sqv, imgi, cnt);
    scan_kernel<<<1, N_IMG, 0, stream>>>(cnt, startb, cursor);
    scatter_kernel<<<gridRows, blk, 0, stream>>>(imgi, cursor, perm);

    // ---- KNN top-8 + LN + weight prep, one mega dispatch ----
    lnknnprep_kernel<<<KNN_BLOCKS + LN_BLOCKS + prepBlocks, blk, 0, stream>>>(
        x, ln_v_g, ln_v_b, ln_t_g, ln_t_b, xvh, xth,
        cxv, cyv, sqv, imgi, cnt, startb, perm, kidx, wgt, pa);

    // ---- fv + ft (plain bf16, NF=2) -> baseh ----
    GemmPair fvP{xvh, wv_h, b_v, 1024, 4, 0};
    GemmPair ftP{xth, wt_h, b_t, 768, 4, 256};
    gemm2_kernel<4, 2><<<1024, blk, 0, stream>>>(fvP, ftP, 512, baseh, FD_DIM,
                                                 nullptr, nullptr);

    // ---- class prior + gi concat + neigh_agg ----
    post_base_kernel<<<B_ROWS, blk, 0, stream>>>(baseh, W_cp, b_cp, kidx, wgt, gih, aggh);

    // ---- ctx1+ctx2 fused -> gi[:, 517:773] ----
    ctxfused_kernel<<<256, blk, 0, stream>>>(aggh, wx1_h, b_ctx1, wx2_h, b_ctx2, gih);

    // ---- g1 + gate fused (32-row panels, 256 blocks) ----
    g1gate_kernel<<<256, blk, 0, stream>>>(gih, wg1_h, b_g1, W_g2, b_g2, gp, entpart);

    // ---- spatial update (NF=2 -> 1024 blocks each for occupancy) ----
    gather_gate_kernel<<<B_ROWS, blk, 0, stream>>>(baseh, kidx, wgt, gp, aggh);
    GemmPair u1P{aggh, wu1_h, b_gu1, 512, 8, 0};
    gemm2_kernel<3, 2><<<1024, blk, 0, stream>>>(u1P, u1P, 1024, guh, FD_DIM,
                                                 nullptr, nullptr);
    GemmPair u2P{guh, wu2_h, b_gu2, 512, 8, 0};
    gemm2_kernel<5, 2><<<1024, blk, 0, stream>>>(u2P, u2P, 1024, fusedh, FD_DIM,
                                                 baseh, gp);

    // ---- classifier head fused (+ entropy finalize) ----
    c1logits_kernel<<<256, blk, 0, stream>>>(fusedh, wc1_h, b_c1, bn_g, bn_b,
                                             W_c2, b_c2, entpart, out);

    (void)in_sizes; (void)n_in; (void)out_size; (void)ws_size;
}